// Round 16
// baseline (243.300 us; speedup 1.0000x reference)
//
#include <hip/hip_runtime.h>
#include <hip/hip_bf16.h>

// SelfAttention (B=4, C=128, H=W=64), fp32 I/O.
// out[b,c,i] = X[b,c,i] + sum_j exp(S[i,j]) * rinv_j * V[j,c],
//   S = Q K^T, rinv_j = 1/sum_i exp(S[i,j])   (softmax over query axis)
// S via split-bf16 (hi+lo) 3-term MFMA emulation (precision-critical).
// Q materialized in B-fragment image by proj; P = exp(S) in B-frag image by
// stats (barrier-free, LDS-free); V' in A-frag image by scalev; attnp is a
// barrier-free streaming GEMM with plain stores (no atomics); final8 reduces.

typedef unsigned short u16;
typedef __attribute__((ext_vector_type(8))) __bf16 bf16x8;
typedef __attribute__((ext_vector_type(8))) unsigned short us8;
typedef __attribute__((ext_vector_type(4))) float f32x4;
typedef __attribute__((ext_vector_type(16))) float f32x16;

#define NB 4
#define CH 128
#define NP 4096
#define ISPL 16   // stats i-splits
#define JSPLF 4   // fallback attn j-splits
#define JSPLP 8   // P-path attn j-splits

__device__ __forceinline__ float bf2f(u16 b){ union{float f;unsigned u;}v; v.u=((unsigned)b)<<16; return v.f; }
__device__ __forceinline__ u16 f2bf(float f){ union{float f;unsigned u;}v; v.f=f; unsigned r=v.u + 0x7FFFu + ((v.u>>16)&1u); return (u16)(r>>16); }

__device__ __forceinline__ f32x4 mfma16(bf16x8 a, bf16x8 b, f32x4 c){
  return __builtin_amdgcn_mfma_f32_16x16x32_bf16(a, b, c, 0, 0, 0);
}
__device__ __forceinline__ f32x16 mfma32(bf16x8 a, bf16x8 b, f32x16 c){
  return __builtin_amdgcn_mfma_f32_32x32x16_bf16(a, b, c, 0, 0, 0);
}
__device__ __forceinline__ bf16x8 ld8(const u16* p){
  union { us8 u; bf16x8 b; } v; v.u = *(const us8*)p; return v.b;
}
__device__ __forceinline__ void split8(const float* p, bf16x8& h, bf16x8& l){
  union { us8 u; bf16x8 b; } uh, ul;
  #pragma unroll
  for (int e=0;e<8;++e){
    float f = p[e];
    u16 hb = f2bf(f);
    uh.u[e] = hb;
    ul.u[e] = f2bf(f - bf2f(hb));
  }
  h = uh.b; l = ul.b;
}
__device__ __forceinline__ unsigned pk2(float a, float b){
  float2 f2; f2.x = a; f2.y = b;
  __hip_bfloat162 hb = __float22bfloat162_rn(f2);
  unsigned u; __builtin_memcpy(&u, &hb, 4);
  return u;
}
// C/D-layout p[8] (one k-tile) -> P^T B-fragment (lane n=i, k=h*8+e).
__device__ __forceinline__ us8 pfrag(const float* p, bool hb1){
  unsigned hA = pk2(p[0], p[1]);
  unsigned hB = pk2(p[2], p[3]);
  unsigned hC = pk2(p[4], p[5]);
  unsigned hD = pk2(p[6], p[7]);
  unsigned s0h = hb1? hA:hC, s1h = hb1? hB:hD;
  unsigned r0h = __shfl_xor(s0h, 32), r1h = __shfl_xor(s1h, 32);
  unsigned dh[4];
  dh[0] = hb1? r0h : hA;  dh[1] = hb1? r1h : hB;
  dh[2] = hb1? hC  : r0h; dh[3] = hb1? hD  : r1h;
  us8 o; __builtin_memcpy(&o, dh, 16); return o;
}
__device__ __forceinline__ void gll16(const void* g, void* l){
  __builtin_amdgcn_global_load_lds((const __attribute__((address_space(1))) void*)g,
                                   (__attribute__((address_space(3))) void*)l, 16, 0, 0);
}

// ---------------------------------------------------------------------------
// Kernel 0: pre-split the three 128x128 weight matrices into bf16 hi/lo.
// ---------------------------------------------------------------------------
__global__ __launch_bounds__(256) void wsplit_kernel(
    const float* __restrict__ Wq, const float* __restrict__ Wk,
    const float* __restrict__ Wv, u16* __restrict__ Whi, u16* __restrict__ Wlo)
{
  const int m = blockIdx.y;
  const float* W = (m==0) ? Wq : (m==1) ? Wk : Wv;
  int i = blockIdx.x*256 + threadIdx.x;
  float f = W[i];
  u16 hb = f2bf(f);
  Whi[m*CH*CH + i] = hb;
  Wlo[m*CH*CH + i] = f2bf(f - bf2f(hb));
}

// ---------------------------------------------------------------------------
// Kernel 1: projections (one wave per 16-pixel tile), 16x16x32 MFMA.
// Q written either row-major [b][i][ch] (qfrag=0, fallback) or in the
// B-fragment image [b][i>>5][k>>3][i&31]x8 (qfrag=1, P path).
// ---------------------------------------------------------------------------
__global__ __launch_bounds__(64) void proj_kernel(
    const float* __restrict__ X,
    const u16* __restrict__ Whi, const u16* __restrict__ Wlo,
    const float* __restrict__ bq, const float* __restrict__ bk,
    const float* __restrict__ bv,
    u16* __restrict__ Qdh, u16* __restrict__ Qdl, int qfrag,
    u16* __restrict__ Khi, u16* __restrict__ Klo,
    u16* __restrict__ Vthi, u16* __restrict__ Vtlo)
{
  __shared__ float XT[16][CH+4];
  const int b = blockIdx.y, p0 = blockIdx.x*16, lane = threadIdx.x;
  #pragma unroll
  for (int h=0; h<2; ++h){
    int c = lane + h*64;
    const float* src = X + ((size_t)b*CH + c)*NP + p0;
    #pragma unroll
    for (int v4=0; v4<4; ++v4){
      f32x4 v = *(const f32x4*)(src + v4*4);
      #pragma unroll
      for (int p=0;p<4;++p) XT[v4*4+p][c] = v[p];
    }
  }
  __syncthreads();
  const int l15 = lane&15, quad = lane>>4;
  bf16x8 xh[4], xl[4];
  #pragma unroll
  for (int s=0;s<4;++s) split8(&XT[l15][s*32+quad*8], xh[s], xl[s]);

  const float* bm[2] = {bq, bk};
  #pragma unroll
  for (int m=0;m<2;++m){
    const u16* WH = Whi + m*CH*CH;
    const u16* WL = Wlo + m*CH*CH;
    #pragma unroll
    for (int nt=0;nt<8;++nt){
      f32x4 a = {0.f,0.f,0.f,0.f};
      #pragma unroll
      for (int s=0;s<4;++s){
        size_t g = (size_t)(nt*16+l15)*CH + s*32 + quad*8;
        bf16x8 wh = ld8(&WH[g]), wl = ld8(&WL[g]);
        a = mfma16(xh[s], wl, a);
        a = mfma16(xl[s], wh, a);
        a = mfma16(xh[s], wh, a);
      }
      int o = nt*16 + l15;
      float bias = bm[m][o];
      #pragma unroll
      for (int r=0;r<4;++r){
        int i = p0 + quad*4 + r;
        float q = a[r] + bias;
        u16 hb = f2bf(q);
        u16 lb = f2bf(q - bf2f(hb));
        if (m == 0){
          if (qfrag){
            size_t idx = ((size_t)(b*128 + (i>>5))*16 + (o>>3))*256
                       + (size_t)(i&31)*8 + (o&7);
            Qdh[idx] = hb; Qdl[idx] = lb;
          } else {
            size_t idx = ((size_t)b*NP + i)*CH + o;
            Qdh[idx] = hb; Qdl[idx] = lb;
          }
        } else {
          size_t idx = ((size_t)b*NP + i)*CH + o;
          Khi[idx] = hb; Klo[idx] = lb;
        }
      }
    }
  }
  const u16* WH = Whi + 2*CH*CH;
  const u16* WL = Wlo + 2*CH*CH;
  #pragma unroll
  for (int mt=0;mt<8;++mt){
    f32x4 a = {0.f,0.f,0.f,0.f};
    #pragma unroll
    for (int s=0;s<4;++s){
      size_t g = (size_t)(mt*16+l15)*CH + s*32 + quad*8;
      bf16x8 wh = ld8(&WH[g]), wl = ld8(&WL[g]);
      a = mfma16(wh, xl[s], a);
      a = mfma16(wl, xh[s], a);
      a = mfma16(wh, xh[s], a);
    }
    #pragma unroll
    for (int r=0;r<4;++r){
      int co = mt*16 + quad*4 + r;
      float v = a[r] + bv[co];
      u16 hb = f2bf(v);
      size_t idx = ((size_t)b*CH + co)*NP + p0 + l15;
      Vthi[idx] = hb;
      Vtlo[idx] = f2bf(v - bf2f(hb));
    }
  }
}

// ---------------------------------------------------------------------------
// Kernel 2a (P path): barrier-free, LDS-free stats. K frags register-resident;
// Q B-frags loaded coalesced from the fragment image. Emits P B-frag image
// and partial column sums. Grid (NP/128 j, ISPL i, NB).
// ---------------------------------------------------------------------------
__global__ __launch_bounds__(256,3) void statsb_kernel(
    const u16* __restrict__ Qfh, const u16* __restrict__ Qfl,
    const u16* __restrict__ Khi, const u16* __restrict__ Klo,
    float* __restrict__ colpart, u16* __restrict__ Pbuf)
{
  const int b = blockIdx.z, isplit = blockIdx.y;
  const int tid = threadIdx.x, lane = tid&63, w = tid>>6;
  const int l31 = lane&31, h = lane>>5;
  const int j0w = blockIdx.x*128 + w*32;
  const bool hb1 = (h != 0);

  bf16x8 kh[8], kl[8];
  #pragma unroll
  for (int ks=0;ks<8;++ks){
    size_t g = ((size_t)b*NP + j0w + l31)*CH + ks*16 + h*8;
    kh[ks] = ld8(&Khi[g]);
    kl[ks] = ld8(&Klo[g]);
  }

  const int NCH = (NP/ISPL)/32;     // 8 chunks of 32 i
  const int itbase = isplit*NCH;
  const size_t Pjt = ((size_t)(b*128 + blockIdx.x*4 + w))*((size_t)4*NP*8);

  float scol[16];
  #pragma unroll
  for (int r=0;r<16;++r) scol[r] = 0.f;

  for (int ic=0; ic<NCH; ++ic){
    const int it = itbase + ic;
    const size_t qbase = (size_t)(b*128 + it)*(16*256);
    f32x16 s;
    #pragma unroll
    for (int r=0;r<16;++r) s[r] = 0.f;
    #pragma unroll
    for (int ks=0;ks<8;++ks){
      size_t qo = qbase + (size_t)((ks*2+h)*256) + (size_t)l31*8;
      bf16x8 qbh = ld8(&Qfh[qo]);
      bf16x8 qbl = ld8(&Qfl[qo]);
      s = mfma32(kh[ks], qbl, s);
      s = mfma32(kl[ks], qbh, s);
      s = mfma32(kh[ks], qbh, s);
    }
    float p[16];
    #pragma unroll
    for (int r=0;r<16;++r){ p[r] = __expf(s[r]); scol[r] += p[r]; }
    const int iglob = it*32 + l31;
    #pragma unroll
    for (int t=0;t<2;++t){
      us8 frag = pfrag(&p[8*t], hb1);
      *(us8*)&Pbuf[Pjt + ((size_t)((t*2+h)*NP) + iglob)*8] = frag;
    }
  }
  #pragma unroll
  for (int m=1; m<32; m<<=1){
    #pragma unroll
    for (int r=0;r<16;++r) scol[r] += __shfl_xor(scol[r], m);
  }
  if (l31 == 0){
    #pragma unroll
    for (int r=0;r<16;++r){
      int j = j0w + (r&3) + 8*(r>>2) + 4*h;
      colpart[((size_t)(isplit*NB + b))*NP + j] = scol[r];
    }
  }
}

// ---------------------------------------------------------------------------
// Kernel 2b (fallback): LDS-staged stats over row-major Q (no P store).
// ---------------------------------------------------------------------------
__global__ __launch_bounds__(256,3) void statsf_kernel(
    const u16* __restrict__ Qhi, const u16* __restrict__ Qlo,
    const u16* __restrict__ Khi, const u16* __restrict__ Klo,
    float* __restrict__ colpart)
{
  __shared__ u16 SQ[2][2][32*CH];
  const int b = blockIdx.z, isplit = blockIdx.y;
  const int tid = threadIdx.x, lane = tid&63, w = tid>>6;
  const int l31 = lane&31, h = lane>>5;
  const int j0w = blockIdx.x*128 + w*32;

  const int slot0 = w*128 + lane, slot1 = slot0 + 64;
  const int qr0 = slot0&31, qc0 = slot0>>5, qr1 = slot1&31, qc1 = slot1>>5;
  const size_t qg0 = ((size_t)b*NP + qr0)*CH + qc0*8;
  const size_t qg1 = ((size_t)b*NP + qr1)*CH + qc1*8;
  const int lof0 = slot0*8, lof1 = slot1*8;

  bf16x8 kh[8], kl[8];
  #pragma unroll
  for (int ks=0;ks<8;++ks){
    size_t g = ((size_t)b*NP + j0w + l31)*CH + ks*16 + h*8;
    kh[ks] = ld8(&Khi[g]);
    kl[ks] = ld8(&Klo[g]);
  }

  const int ibase = isplit*(NP/ISPL);
  const int NCH = (NP/ISPL)/32;

  auto stageQ = [&](int t){
    size_t iofs = (size_t)(ibase + t*32)*CH;
    int bf = t&1;
    gll16(&Qhi[qg0 + iofs], &SQ[bf][0][lof0]);
    gll16(&Qhi[qg1 + iofs], &SQ[bf][0][lof1]);
    gll16(&Qlo[qg0 + iofs], &SQ[bf][1][lof0]);
    gll16(&Qlo[qg1 + iofs], &SQ[bf][1][lof1]);
  };
  auto computeS = [&](int t, f32x16& s){
    const u16* Qh = &SQ[t&1][0][0];
    const u16* Ql = &SQ[t&1][1][0];
    #pragma unroll
    for (int r=0;r<16;++r) s[r] = 0.f;
    #pragma unroll
    for (int ks=0;ks<8;++ks){
      int o = (ks*2+h)*256 + l31*8;
      bf16x8 qbh = ld8(&Qh[o]);
      bf16x8 qbl = ld8(&Ql[o]);
      s = mfma32(kh[ks], qbl, s);
      s = mfma32(kl[ks], qbh, s);
      s = mfma32(kh[ks], qbh, s);
    }
  };

  stageQ(0); if (NCH > 1) stageQ(1);
  __syncthreads();
  f32x16 s;
  computeS(0, s);
  __syncthreads();

  float scol[16];
  #pragma unroll
  for (int r=0;r<16;++r) scol[r] = 0.f;

  for (int ic=0; ic<NCH; ++ic){
    if (ic+2 < NCH) stageQ(ic+2);
    #pragma unroll
    for (int r=0;r<16;++r) scol[r] += __expf(s[r]);
    if (ic+1 < NCH) computeS(ic+1, s);
    __syncthreads();
  }
  #pragma unroll
  for (int m=1; m<32; m<<=1){
    #pragma unroll
    for (int r=0;r<16;++r) scol[r] += __shfl_xor(scol[r], m);
  }
  if (l31 == 0){
    #pragma unroll
    for (int r=0;r<16;++r){
      int j = j0w + (r&3) + 8*(r>>2) + 4*h;
      colpart[((size_t)(isplit*NB + b))*NP + j] = scol[r];
    }
  }
}

// ---------------------------------------------------------------------------
// Kernel 3: V' = rinv_j * V -> bf16: in-place hi (for fallback) AND, when
// Vfrag != nullptr, the A-fragment image Vfrag[b][jtile][kchunk(4)][c(128)]x8.
// ---------------------------------------------------------------------------
__global__ __launch_bounds__(256) void scalev_kernel(
    u16* __restrict__ Vthi, const u16* __restrict__ Vtlo,
    const float* __restrict__ colpart, u16* __restrict__ Vfrag)
{
  size_t t = (size_t)blockIdx.x*256 + threadIdx.x;
  size_t base = t*8;
  int bc = (int)(base >> 12);
  int b  = bc >> 7;
  int c  = bc & 127;
  int j0 = (int)(base & (NP-1));
  f32x4 s0 = {0.f,0.f,0.f,0.f}, s1 = {0.f,0.f,0.f,0.f};
  #pragma unroll
  for (int k=0;k<ISPL;++k){
    const float* cp = &colpart[((size_t)(k*NB + b))*NP + j0];
    f32x4 a0 = *(const f32x4*)cp;
    f32x4 a1 = *(const f32x4*)(cp+4);
    #pragma unroll
    for (int e=0;e<4;++e){ s0[e]+=a0[e]; s1[e]+=a1[e]; }
  }
  us8 hh = *(const us8*)&Vthi[base];
  us8 ll = *(const us8*)&Vtlo[base];
  us8 oh;
  #pragma unroll
  for (int e=0;e<8;++e){
    float r = 1.0f / (e<4 ? s0[e] : s1[e-4]);
    float v = (bf2f(hh[e]) + bf2f(ll[e])) * r;
    oh[e] = f2bf(v);
  }
  *(us8*)&Vthi[base] = oh;
  if (Vfrag){
    int jt = j0 >> 5;
    int kc = ((j0 >> 4) & 1)*2 + ((j0 >> 3) & 1);
    size_t o = (((size_t)(b*128 + jt))*4 + kc)*((size_t)CH*8) + (size_t)c*8;
    *(us8*)&Vfrag[o] = oh;
  }
}

// ---------------------------------------------------------------------------
// Kernel 4: out := X   (fallback path seed only)
// ---------------------------------------------------------------------------
__global__ __launch_bounds__(256) void copyx_kernel(
    const float* __restrict__ X, float* __restrict__ out)
{
  size_t idx = ((size_t)blockIdx.x*256 + threadIdx.x)*4;
  *(f32x4*)&out[idx] = *(const f32x4*)&X[idx];
}

// ---------------------------------------------------------------------------
// Kernel 5a (P path): barrier-free, LDS-free streaming P@V'.
// Both operands are fragment-image arrays (all loads coalesced 16B/lane).
// Partials go to xpart[jsplit] with PLAIN stores — no atomics.
// ---------------------------------------------------------------------------
__global__ __launch_bounds__(256,4) void attnp_kernel(
    const u16* __restrict__ Pbuf, const u16* __restrict__ Vfrag,
    float* __restrict__ xpart)
{
  const int b = blockIdx.z, jsplit = blockIdx.y;
  const int tid = threadIdx.x, lane = tid&63, w = tid>>6;
  const int l31 = lane&31, h = lane>>5;
  const int i0w = blockIdx.x*128 + w*32;

  const int NJT = (NP/JSPLP)/32;   // 16 j-tiles of 32

  f32x16 acc[4];
  #pragma unroll
  for (int mt=0;mt<4;++mt)
    #pragma unroll
    for (int r=0;r<16;++r) acc[mt][r] = 0.f;

  for (int jt=0; jt<NJT; ++jt){
    const int jtg = jsplit*NJT + jt;               // global j-tile 0..127
    const size_t Pjt = ((size_t)(b*128 + jtg))*((size_t)4*NP*8);
    const size_t Vjt = ((size_t)(b*128 + jtg))*((size_t)4*CH*8);
    #pragma unroll
    for (int t=0;t<2;++t){
      bf16x8 Bh = ld8(&Pbuf[Pjt + ((size_t)((t*2+h)*NP) + i0w + l31)*8]);
      #pragma unroll
      for (int mt=0;mt<4;++mt){
        bf16x8 vh = ld8(&Vfrag[Vjt + (size_t)((t*2+h)*CH + mt*32 + l31)*8]);
        acc[mt] = mfma32(vh, Bh, acc[mt]);
      }
    }
  }
  float* xp = xpart + ((size_t)(jsplit*NB + b))*(size_t)CH*NP;
  #pragma unroll
  for (int mt=0;mt<4;++mt){
    #pragma unroll
    for (int r=0;r<16;++r){
      int c = mt*32 + (r&3) + 8*(r>>2) + 4*h;
      xp[(size_t)c*NP + i0w + l31] = acc[mt][r];
    }
  }
}

// ---------------------------------------------------------------------------
// Kernel 5a': out = X + sum_{k<JSPLP} xpart[k]
// ---------------------------------------------------------------------------
__global__ __launch_bounds__(256) void final8_kernel(
    const float* __restrict__ X, const float* __restrict__ xpart,
    float* __restrict__ out)
{
  const size_t n = (size_t)NB*CH*NP;
  size_t idx = ((size_t)blockIdx.x*256 + threadIdx.x)*4;
  f32x4 s = *(const f32x4*)&X[idx];
  #pragma unroll
  for (int k=0;k<JSPLP;++k){
    f32x4 p = *(const f32x4*)&xpart[(size_t)k*n + idx];
    #pragma unroll
    for (int e=0;e<4;++e) s[e] += p[e];
  }
  *(f32x4*)&out[idx] = s;
}

// ---------------------------------------------------------------------------
// Kernel 5b (fallback, ws too small): flash attn (atomics into out).
// ---------------------------------------------------------------------------
__global__ __launch_bounds__(256,2) void attnf_kernel(
    const u16* __restrict__ Qhi, const u16* __restrict__ Qlo,
    const u16* __restrict__ Khi, const u16* __restrict__ Klo,
    const u16* __restrict__ Vthi,
    float* __restrict__ out)
{
  __shared__ u16 SK[2][2][32*CH];
  __shared__ u16 SV[2][4*CH*8];
  const int b = blockIdx.z, jsplit = blockIdx.y;
  const int tid = threadIdx.x, lane = tid&63, w = tid>>6;
  const int l31 = lane&31, h = lane>>5;
  const int i0w = blockIdx.x*128 + w*32;
  const bool hb1 = (h != 0);

  const int slot0 = tid, slot1 = tid + 256;
  const int kr0 = slot0&31, kc0 = slot0>>5, kr1 = slot1&31, kc1 = slot1>>5;
  const size_t kg0 = ((size_t)b*NP + kr0)*CH + kc0*8;
  const size_t kg1 = ((size_t)b*NP + kr1)*CH + kc1*8;
  const size_t vg0 = ((size_t)b*CH + (slot0&127))*NP + (slot0>>7)*8;
  const size_t vg1 = ((size_t)b*CH + (slot1&127))*NP + (slot1>>7)*8;
  const int lof0 = slot0*8, lof1 = slot1*8;

  const int jbase = jsplit*(NP/JSPLF);
  const int NJT = (NP/JSPLF)/32;

  auto stageK = [&](int t){
    size_t jofs = (size_t)(jbase + t*32)*CH;
    int bf = t&1;
    gll16(&Khi[kg0 + jofs], &SK[bf][0][lof0]);
    gll16(&Khi[kg1 + jofs], &SK[bf][0][lof1]);
    gll16(&Klo[kg0 + jofs], &SK[bf][1][lof0]);
    gll16(&Klo[kg1 + jofs], &SK[bf][1][lof1]);
  };
  auto stageV = [&](int t){
    int j0 = jbase + t*32;
    int bf = t&1;
    gll16(&Vthi[vg0 + j0], &SV[bf][lof0]);
    gll16(&Vthi[vg1 + j0], &SV[bf][lof1]);
  };

  bf16x8 qh[8], ql[8];
  #pragma unroll
  for (int ks=0;ks<8;++ks){
    size_t g = ((size_t)b*NP + i0w + l31)*CH + ks*16 + h*8;
    qh[ks] = ld8(&Qhi[g]); ql[ks] = ld8(&Qlo[g]);
  }

  auto computeS = [&](int t, f32x16& s){
    const u16* Kh = &SK[t&1][0][0];
    const u16* Kl = &SK[t&1][1][0];
    #pragma unroll
    for (int r=0;r<16;++r) s[r] = 0.f;
    #pragma unroll
    for (int ks=0;ks<8;++ks){
      int o = (ks*2+h)*256 + l31*8;
      bf16x8 ah = ld8(&Kh[o]);
      bf16x8 al = ld8(&Kl[o]);
      s = mfma32(ah, ql[ks], s);
      s = mfma32(al, qh[ks], s);
      s = mfma32(ah, qh[ks], s);
    }
  };

  f32x16 acc[4];
  #pragma unroll
  for (int mt=0;mt<4;++mt)
    #pragma unroll
    for (int r=0;r<16;++r) acc[mt][r] = 0.f;

  stageK(0); stageV(0); stageK(1);
  __syncthreads();
  f32x16 s;
  computeS(0, s);
  __syncthreads();

  for (int jt=0; jt<NJT; ++jt){
    const int cb = jt&1;
    if (jt+2 < NJT) stageK(jt+2);
    if (jt+1 < NJT) stageV(jt+1);

    float p[16];
    #pragma unroll
    for (int r=0;r<16;++r) p[r] = __expf(s[r]);

    if (jt+1 < NJT) computeS(jt+1, s);

    const u16* Vh = &SV[cb][0];
    #pragma unroll
    for (int t=0;t<2;++t){
      us8 fr = pfrag(&p[8*t], hb1);
      bf16x8 Bh; __builtin_memcpy(&Bh, &fr, 16);
      #pragma unroll
      for (int mt=0;mt<4;++mt){
        int o = (t*2+h)*1024 + (mt*32+l31)*8;
        bf16x8 vh = ld8(&Vh[o]);
        acc[mt] = mfma32(vh, Bh, acc[mt]);
      }
    }
    __syncthreads();
  }
  float* xp = out + (size_t)b*CH*NP;
  #pragma unroll
  for (int mt=0;mt<4;++mt){
    #pragma unroll
    for (int r=0;r<16;++r){
      int c = mt*32 + (r&3) + 8*(r>>2) + 4*h;
      atomicAdd(&xp[(size_t)c*NP + i0w + l31], acc[mt][r]);
    }
  }
}

extern "C" void kernel_launch(void* const* d_in, const int* in_sizes, int n_in,
                              void* d_out, int out_size, void* d_ws, size_t ws_size,
                              hipStream_t stream)
{
  const float* X  = (const float*)d_in[0];
  const float* Wq = (const float*)d_in[1];
  const float* bq = (const float*)d_in[2];
  const float* Wk = (const float*)d_in[3];
  const float* bk = (const float*)d_in[4];
  const float* Wv = (const float*)d_in[5];
  const float* bv = (const float*)d_in[6];
  float* outp = (float*)d_out;

  const size_t n = (size_t)NB*NP*CH;        // 2,097,152
  u16* Qa  = (u16*)d_ws;                    // Q storage (frag image OR row-major)
  u16* Qb  = Qa + n;
  u16* Khi = Qb + n;
  u16* Klo = Khi + n;
  u16* Vthi = Klo + n;
  u16* Vtlo = Vthi + n;
  u16* Whi  = Vtlo + n;
  u16* Wlo  = Whi + 3*CH*CH;
  float* colpart = (float*)(Wlo + 3*CH*CH);      // ISPL*NB*NP floats
  u16* Pbuf = (u16*)(colpart + (size_t)ISPL*NB*NP);
  const size_t pelems = (size_t)NB*128*4*NP*8;   // 67,108,864 u16 = 128 MiB
  u16* Vfrag = Pbuf + pelems;                    // n u16 = 4 MiB
  float* xpart = (float*)(Vfrag + n);            // JSPLP*n fp32 = 64 MiB

  const size_t need = (size_t)((char*)xpart - (char*)d_ws)
                      + (size_t)JSPLP*n*sizeof(float);
  const bool usep = (ws_size >= need);

  wsplit_kernel<<<dim3(CH*CH/256, 3),      256, 0, stream>>>(Wq, Wk, Wv, Whi, Wlo);
  proj_kernel  <<<dim3(NP/16, NB),          64, 0, stream>>>(
      X, Whi, Wlo, bq, bk, bv, Qa, Qb, usep ? 1 : 0,
      Khi, Klo, Vthi, Vtlo);
  if (usep){
    statsb_kernel<<<dim3(NP/128, ISPL, NB), 256, 0, stream>>>(
        Qa, Qb, Khi, Klo, colpart, Pbuf);
    scalev_kernel<<<dim3(n/(256*8)),       256, 0, stream>>>(Vthi, Vtlo, colpart, Vfrag);
    attnp_kernel <<<dim3(NP/128, JSPLP, NB), 256, 0, stream>>>(Pbuf, Vfrag, xpart);
    final8_kernel<<<dim3(n/(256*4)),       256, 0, stream>>>(X, xpart, outp);
  } else {
    statsf_kernel<<<dim3(NP/128, ISPL, NB), 256, 0, stream>>>(
        Qa, Qb, Khi, Klo, colpart);
    scalev_kernel<<<dim3(n/(256*8)),       256, 0, stream>>>(Vthi, Vtlo, colpart,
                                                             (u16*)nullptr);
    copyx_kernel <<<dim3(n/(256*4)),       256, 0, stream>>>(X, outp);
    attnf_kernel <<<dim3(NP/128, JSPLF, NB), 256, 0, stream>>>(
        Qa, Qb, Khi, Klo, Vthi, outp);
  }
}

// Round 17
// 226.361 us; speedup vs baseline: 1.0748x; 1.0748x over previous
//
#include <hip/hip_runtime.h>
#include <hip/hip_bf16.h>

// SelfAttention (B=4, C=128, H=W=64), fp32 I/O.
// out[b,c,i] = X[b,c,i] + sum_j exp(S[i,j]) * rinv_j * V[j,c],
//   S = Q K^T, rinv_j = 1/sum_i exp(S[i,j])   (softmax over query axis)
// S via split-bf16 (hi+lo) 3-term MFMA emulation (precision-critical).
// stats: LDS-shared Q staging (4-wave reuse), dbuf-pipelined, emits P=exp(S)
// in bf16 B-fragment image + column-sum partials (ISPL=16 for supply).
// scalev: V' in A-fragment image. attnp: barrier-free LDS-free streaming
// P@V' GEMM, bf16 partials via plain stores (no atomics). final8 reduces.

typedef unsigned short u16;
typedef __attribute__((ext_vector_type(8))) __bf16 bf16x8;
typedef __attribute__((ext_vector_type(8))) unsigned short us8;
typedef __attribute__((ext_vector_type(4))) unsigned short us4;
typedef __attribute__((ext_vector_type(4))) float f32x4;
typedef __attribute__((ext_vector_type(16))) float f32x16;

#define NB 4
#define CH 128
#define NP 4096
#define ISPL 16   // stats i-splits
#define JSPLF 4   // fallback attn j-splits
#define JSPLP 8   // P-path attn j-splits

__device__ __forceinline__ float bf2f(u16 b){ union{float f;unsigned u;}v; v.u=((unsigned)b)<<16; return v.f; }
__device__ __forceinline__ u16 f2bf(float f){ union{float f;unsigned u;}v; v.f=f; unsigned r=v.u + 0x7FFFu + ((v.u>>16)&1u); return (u16)(r>>16); }

__device__ __forceinline__ f32x4 mfma16(bf16x8 a, bf16x8 b, f32x4 c){
  return __builtin_amdgcn_mfma_f32_16x16x32_bf16(a, b, c, 0, 0, 0);
}
__device__ __forceinline__ f32x16 mfma32(bf16x8 a, bf16x8 b, f32x16 c){
  return __builtin_amdgcn_mfma_f32_32x32x16_bf16(a, b, c, 0, 0, 0);
}
__device__ __forceinline__ bf16x8 ld8(const u16* p){
  union { us8 u; bf16x8 b; } v; v.u = *(const us8*)p; return v.b;
}
__device__ __forceinline__ void split8(const float* p, bf16x8& h, bf16x8& l){
  union { us8 u; bf16x8 b; } uh, ul;
  #pragma unroll
  for (int e=0;e<8;++e){
    float f = p[e];
    u16 hb = f2bf(f);
    uh.u[e] = hb;
    ul.u[e] = f2bf(f - bf2f(hb));
  }
  h = uh.b; l = ul.b;
}
__device__ __forceinline__ unsigned pk2(float a, float b){
  float2 f2; f2.x = a; f2.y = b;
  __hip_bfloat162 hb = __float22bfloat162_rn(f2);
  unsigned u; __builtin_memcpy(&u, &hb, 4);
  return u;
}
// C/D-layout p[8] (one k-tile) -> P^T B-fragment (lane n=i, k=h*8+e).
__device__ __forceinline__ us8 pfrag(const float* p, bool hb1){
  unsigned hA = pk2(p[0], p[1]);
  unsigned hB = pk2(p[2], p[3]);
  unsigned hC = pk2(p[4], p[5]);
  unsigned hD = pk2(p[6], p[7]);
  unsigned s0h = hb1? hA:hC, s1h = hb1? hB:hD;
  unsigned r0h = __shfl_xor(s0h, 32), r1h = __shfl_xor(s1h, 32);
  unsigned dh[4];
  dh[0] = hb1? r0h : hA;  dh[1] = hb1? r1h : hB;
  dh[2] = hb1? hC  : r0h; dh[3] = hb1? hD  : r1h;
  us8 o; __builtin_memcpy(&o, dh, 16); return o;
}
__device__ __forceinline__ void gll16(const void* g, void* l){
  __builtin_amdgcn_global_load_lds((const __attribute__((address_space(1))) void*)g,
                                   (__attribute__((address_space(3))) void*)l, 16, 0, 0);
}

// ---------------------------------------------------------------------------
// Kernel 0: pre-split the three 128x128 weight matrices into bf16 hi/lo.
// ---------------------------------------------------------------------------
__global__ __launch_bounds__(256) void wsplit_kernel(
    const float* __restrict__ Wq, const float* __restrict__ Wk,
    const float* __restrict__ Wv, u16* __restrict__ Whi, u16* __restrict__ Wlo)
{
  const int m = blockIdx.y;
  const float* W = (m==0) ? Wq : (m==1) ? Wk : Wv;
  int i = blockIdx.x*256 + threadIdx.x;
  float f = W[i];
  u16 hb = f2bf(f);
  Whi[m*CH*CH + i] = hb;
  Wlo[m*CH*CH + i] = f2bf(f - bf2f(hb));
}

// ---------------------------------------------------------------------------
// Kernel 1: projections (one wave per 16-pixel tile), 16x16x32 MFMA.
// ---------------------------------------------------------------------------
__global__ __launch_bounds__(64) void proj_kernel(
    const float* __restrict__ X,
    const u16* __restrict__ Whi, const u16* __restrict__ Wlo,
    const float* __restrict__ bq, const float* __restrict__ bk,
    const float* __restrict__ bv,
    u16* __restrict__ Qhi, u16* __restrict__ Qlo,
    u16* __restrict__ Khi, u16* __restrict__ Klo,
    u16* __restrict__ Vthi, u16* __restrict__ Vtlo)
{
  __shared__ float XT[16][CH+4];
  const int b = blockIdx.y, p0 = blockIdx.x*16, lane = threadIdx.x;
  #pragma unroll
  for (int h=0; h<2; ++h){
    int c = lane + h*64;
    const float* src = X + ((size_t)b*CH + c)*NP + p0;
    #pragma unroll
    for (int v4=0; v4<4; ++v4){
      f32x4 v = *(const f32x4*)(src + v4*4);
      #pragma unroll
      for (int p=0;p<4;++p) XT[v4*4+p][c] = v[p];
    }
  }
  __syncthreads();
  const int l15 = lane&15, quad = lane>>4;
  bf16x8 xh[4], xl[4];
  #pragma unroll
  for (int s=0;s<4;++s) split8(&XT[l15][s*32+quad*8], xh[s], xl[s]);

  const float* bm[2] = {bq, bk};
  u16* OH[2] = {Qhi, Khi};
  u16* OL[2] = {Qlo, Klo};
  #pragma unroll
  for (int m=0;m<2;++m){
    const u16* WH = Whi + m*CH*CH;
    const u16* WL = Wlo + m*CH*CH;
    #pragma unroll
    for (int nt=0;nt<8;++nt){
      f32x4 a = {0.f,0.f,0.f,0.f};
      #pragma unroll
      for (int s=0;s<4;++s){
        size_t g = (size_t)(nt*16+l15)*CH + s*32 + quad*8;
        bf16x8 wh = ld8(&WH[g]), wl = ld8(&WL[g]);
        a = mfma16(xh[s], wl, a);
        a = mfma16(xl[s], wh, a);
        a = mfma16(xh[s], wh, a);
      }
      int o = nt*16 + l15;
      float bias = bm[m][o];
      #pragma unroll
      for (int r=0;r<4;++r){
        int i = p0 + quad*4 + r;
        float q = a[r] + bias;
        u16 hb = f2bf(q);
        size_t idx = ((size_t)b*NP + i)*CH + o;
        OH[m][idx] = hb;
        OL[m][idx] = f2bf(q - bf2f(hb));
      }
    }
  }
  const u16* WH = Whi + 2*CH*CH;
  const u16* WL = Wlo + 2*CH*CH;
  #pragma unroll
  for (int mt=0;mt<8;++mt){
    f32x4 a = {0.f,0.f,0.f,0.f};
    #pragma unroll
    for (int s=0;s<4;++s){
      size_t g = (size_t)(mt*16+l15)*CH + s*32 + quad*8;
      bf16x8 wh = ld8(&WH[g]), wl = ld8(&WL[g]);
      a = mfma16(wh, xl[s], a);
      a = mfma16(wl, xh[s], a);
      a = mfma16(wh, xh[s], a);
    }
    #pragma unroll
    for (int r=0;r<4;++r){
      int co = mt*16 + quad*4 + r;
      float v = a[r] + bv[co];
      u16 hb = f2bf(v);
      size_t idx = ((size_t)b*CH + co)*NP + p0 + l15;
      Vthi[idx] = hb;
      Vtlo[idx] = f2bf(v - bf2f(hb));
    }
  }
}

// ---------------------------------------------------------------------------
// Kernel 2: S^T = K Q^T (32x32x16, 3-term), LDS-shared Q staging (dbuf,
// software-pipelined). Column sums always; if STOREP, also emit P=exp(S)
// as bf16 B-fragments to Pbuf[b][jtile][kh(4)][i(4096)]x16B.
// ---------------------------------------------------------------------------
template<bool STOREP>
__global__ __launch_bounds__(256,3) void stats_kernel(
    const u16* __restrict__ Qhi, const u16* __restrict__ Qlo,
    const u16* __restrict__ Khi, const u16* __restrict__ Klo,
    float* __restrict__ colpart, u16* __restrict__ Pbuf)
{
  __shared__ u16 SQ[2][2][32*CH];
  const int b = blockIdx.z, isplit = blockIdx.y;
  const int tid = threadIdx.x, lane = tid&63, w = tid>>6;
  const int l31 = lane&31, h = lane>>5;
  const int j0w = blockIdx.x*128 + w*32;
  const bool hb1 = (h != 0);

  const int slot0 = w*128 + lane, slot1 = slot0 + 64;
  const int qr0 = slot0&31, qc0 = slot0>>5, qr1 = slot1&31, qc1 = slot1>>5;
  const size_t qg0 = ((size_t)b*NP + qr0)*CH + qc0*8;
  const size_t qg1 = ((size_t)b*NP + qr1)*CH + qc1*8;
  const int lof0 = slot0*8, lof1 = slot1*8;

  bf16x8 kh[8], kl[8];
  #pragma unroll
  for (int ks=0;ks<8;++ks){
    size_t g = ((size_t)b*NP + j0w + l31)*CH + ks*16 + h*8;
    kh[ks] = ld8(&Khi[g]);
    kl[ks] = ld8(&Klo[g]);
  }

  const int ibase = isplit*(NP/ISPL);
  const int NCH = (NP/ISPL)/32;     // 8 chunks
  const size_t Pjt = ((size_t)(b*128 + blockIdx.x*4 + w))*((size_t)4*NP*8);

  auto stageQ = [&](int t){
    size_t iofs = (size_t)(ibase + t*32)*CH;
    int bf = t&1;
    gll16(&Qhi[qg0 + iofs], &SQ[bf][0][lof0]);
    gll16(&Qhi[qg1 + iofs], &SQ[bf][0][lof1]);
    gll16(&Qlo[qg0 + iofs], &SQ[bf][1][lof0]);
    gll16(&Qlo[qg1 + iofs], &SQ[bf][1][lof1]);
  };
  auto computeS = [&](int t, f32x16& s){
    const u16* Qh = &SQ[t&1][0][0];
    const u16* Ql = &SQ[t&1][1][0];
    #pragma unroll
    for (int r=0;r<16;++r) s[r] = 0.f;
    #pragma unroll
    for (int ks=0;ks<8;++ks){
      int o = (ks*2+h)*256 + l31*8;
      bf16x8 qbh = ld8(&Qh[o]);
      bf16x8 qbl = ld8(&Ql[o]);
      s = mfma32(kh[ks], qbl, s);
      s = mfma32(kl[ks], qbh, s);
      s = mfma32(kh[ks], qbh, s);
    }
  };

  stageQ(0); if (NCH > 1) stageQ(1);
  __syncthreads();
  f32x16 s;
  computeS(0, s);
  __syncthreads();

  float scol[16];
  #pragma unroll
  for (int r=0;r<16;++r) scol[r] = 0.f;

  for (int ic=0; ic<NCH; ++ic){
    if (ic+2 < NCH) stageQ(ic+2);
    float p[16];
    #pragma unroll
    for (int r=0;r<16;++r){ p[r] = __expf(s[r]); scol[r] += p[r]; }
    if (STOREP){
      int iglob = ibase + ic*32 + l31;
      #pragma unroll
      for (int t=0;t<2;++t){
        us8 frag = pfrag(&p[8*t], hb1);
        *(us8*)&Pbuf[Pjt + ((size_t)((t*2+h)*NP) + iglob)*8] = frag;
      }
    }
    if (ic+1 < NCH) computeS(ic+1, s);
    __syncthreads();
  }
  #pragma unroll
  for (int m=1; m<32; m<<=1){
    #pragma unroll
    for (int r=0;r<16;++r) scol[r] += __shfl_xor(scol[r], m);
  }
  if (l31 == 0){
    #pragma unroll
    for (int r=0;r<16;++r){
      int j = j0w + (r&3) + 8*(r>>2) + 4*h;
      colpart[((size_t)(isplit*NB + b))*NP + j] = scol[r];
    }
  }
}

// ---------------------------------------------------------------------------
// Kernel 3: V' = rinv_j * V -> bf16: in-place hi (for fallback) AND, when
// Vfrag != nullptr, the A-fragment image Vfrag[b][jtile][kchunk(4)][c(128)]x8.
// ---------------------------------------------------------------------------
__global__ __launch_bounds__(256) void scalev_kernel(
    u16* __restrict__ Vthi, const u16* __restrict__ Vtlo,
    const float* __restrict__ colpart, u16* __restrict__ Vfrag)
{
  size_t t = (size_t)blockIdx.x*256 + threadIdx.x;
  size_t base = t*8;
  int bc = (int)(base >> 12);
  int b  = bc >> 7;
  int c  = bc & 127;
  int j0 = (int)(base & (NP-1));
  f32x4 s0 = {0.f,0.f,0.f,0.f}, s1 = {0.f,0.f,0.f,0.f};
  #pragma unroll
  for (int k=0;k<ISPL;++k){
    const float* cp = &colpart[((size_t)(k*NB + b))*NP + j0];
    f32x4 a0 = *(const f32x4*)cp;
    f32x4 a1 = *(const f32x4*)(cp+4);
    #pragma unroll
    for (int e=0;e<4;++e){ s0[e]+=a0[e]; s1[e]+=a1[e]; }
  }
  us8 hh = *(const us8*)&Vthi[base];
  us8 ll = *(const us8*)&Vtlo[base];
  us8 oh;
  #pragma unroll
  for (int e=0;e<8;++e){
    float r = 1.0f / (e<4 ? s0[e] : s1[e-4]);
    float v = (bf2f(hh[e]) + bf2f(ll[e])) * r;
    oh[e] = f2bf(v);
  }
  *(us8*)&Vthi[base] = oh;
  if (Vfrag){
    int jt = j0 >> 5;
    int kc = ((j0 >> 4) & 1)*2 + ((j0 >> 3) & 1);
    size_t o = (((size_t)(b*128 + jt))*4 + kc)*((size_t)CH*8) + (size_t)c*8;
    *(us8*)&Vfrag[o] = oh;
  }
}

// ---------------------------------------------------------------------------
// Kernel 4: out := X   (fallback path seed only)
// ---------------------------------------------------------------------------
__global__ __launch_bounds__(256) void copyx_kernel(
    const float* __restrict__ X, float* __restrict__ out)
{
  size_t idx = ((size_t)blockIdx.x*256 + threadIdx.x)*4;
  *(f32x4*)&out[idx] = *(const f32x4*)&X[idx];
}

// ---------------------------------------------------------------------------
// Kernel 5a (P path): barrier-free, LDS-free streaming P@V'.
// Both operands are fragment-image arrays (all loads coalesced 16B/lane).
// Partials stored as bf16 (plain stores, no atomics).
// ---------------------------------------------------------------------------
__global__ __launch_bounds__(256,4) void attnp_kernel(
    const u16* __restrict__ Pbuf, const u16* __restrict__ Vfrag,
    u16* __restrict__ xpart)
{
  const int b = blockIdx.z, jsplit = blockIdx.y;
  const int tid = threadIdx.x, lane = tid&63, w = tid>>6;
  const int l31 = lane&31, h = lane>>5;
  const int i0w = blockIdx.x*128 + w*32;

  const int NJT = (NP/JSPLP)/32;   // 16 j-tiles of 32

  f32x16 acc[4];
  #pragma unroll
  for (int mt=0;mt<4;++mt)
    #pragma unroll
    for (int r=0;r<16;++r) acc[mt][r] = 0.f;

  for (int jt=0; jt<NJT; ++jt){
    const int jtg = jsplit*NJT + jt;               // global j-tile 0..127
    const size_t Pjt = ((size_t)(b*128 + jtg))*((size_t)4*NP*8);
    const size_t Vjt = ((size_t)(b*128 + jtg))*((size_t)4*CH*8);
    #pragma unroll
    for (int t=0;t<2;++t){
      bf16x8 Bh = ld8(&Pbuf[Pjt + ((size_t)((t*2+h)*NP) + i0w + l31)*8]);
      #pragma unroll
      for (int mt=0;mt<4;++mt){
        bf16x8 vh = ld8(&Vfrag[Vjt + (size_t)((t*2+h)*CH + mt*32 + l31)*8]);
        acc[mt] = mfma32(vh, Bh, acc[mt]);
      }
    }
  }
  u16* xp = xpart + ((size_t)(jsplit*NB + b))*(size_t)CH*NP;
  #pragma unroll
  for (int mt=0;mt<4;++mt){
    #pragma unroll
    for (int r=0;r<16;++r){
      int c = mt*32 + (r&3) + 8*(r>>2) + 4*h;
      xp[(size_t)c*NP + i0w + l31] = f2bf(acc[mt][r]);
    }
  }
}

// ---------------------------------------------------------------------------
// Kernel 5a': out = X + sum_{k<JSPLP} bf2f(xpart[k])
// ---------------------------------------------------------------------------
__global__ __launch_bounds__(256) void final8_kernel(
    const float* __restrict__ X, const u16* __restrict__ xpart,
    float* __restrict__ out)
{
  const size_t n = (size_t)NB*CH*NP;
  size_t idx = ((size_t)blockIdx.x*256 + threadIdx.x)*4;
  f32x4 s = *(const f32x4*)&X[idx];
  #pragma unroll
  for (int k=0;k<JSPLP;++k){
    us4 p = *(const us4*)&xpart[(size_t)k*n + idx];
    #pragma unroll
    for (int e=0;e<4;++e) s[e] += bf2f(p[e]);
  }
  *(f32x4*)&out[idx] = s;
}

// ---------------------------------------------------------------------------
// Kernel 5b (fallback, ws too small): flash attn (atomics into out).
// ---------------------------------------------------------------------------
__global__ __launch_bounds__(256,2) void attnf_kernel(
    const u16* __restrict__ Qhi, const u16* __restrict__ Qlo,
    const u16* __restrict__ Khi, const u16* __restrict__ Klo,
    const u16* __restrict__ Vthi,
    float* __restrict__ out)
{
  __shared__ u16 SK[2][2][32*CH];
  __shared__ u16 SV[2][4*CH*8];
  const int b = blockIdx.z, jsplit = blockIdx.y;
  const int tid = threadIdx.x, lane = tid&63, w = tid>>6;
  const int l31 = lane&31, h = lane>>5;
  const int i0w = blockIdx.x*128 + w*32;
  const bool hb1 = (h != 0);

  const int slot0 = tid, slot1 = tid + 256;
  const int kr0 = slot0&31, kc0 = slot0>>5, kr1 = slot1&31, kc1 = slot1>>5;
  const size_t kg0 = ((size_t)b*NP + kr0)*CH + kc0*8;
  const size_t kg1 = ((size_t)b*NP + kr1)*CH + kc1*8;
  const size_t vg0 = ((size_t)b*CH + (slot0&127))*NP + (slot0>>7)*8;
  const size_t vg1 = ((size_t)b*CH + (slot1&127))*NP + (slot1>>7)*8;
  const int lof0 = slot0*8, lof1 = slot1*8;

  const int jbase = jsplit*(NP/JSPLF);
  const int NJT = (NP/JSPLF)/32;

  auto stageK = [&](int t){
    size_t jofs = (size_t)(jbase + t*32)*CH;
    int bf = t&1;
    gll16(&Khi[kg0 + jofs], &SK[bf][0][lof0]);
    gll16(&Khi[kg1 + jofs], &SK[bf][0][lof1]);
    gll16(&Klo[kg0 + jofs], &SK[bf][1][lof0]);
    gll16(&Klo[kg1 + jofs], &SK[bf][1][lof1]);
  };
  auto stageV = [&](int t){
    int j0 = jbase + t*32;
    int bf = t&1;
    gll16(&Vthi[vg0 + j0], &SV[bf][lof0]);
    gll16(&Vthi[vg1 + j0], &SV[bf][lof1]);
  };

  bf16x8 qh[8], ql[8];
  #pragma unroll
  for (int ks=0;ks<8;++ks){
    size_t g = ((size_t)b*NP + i0w + l31)*CH + ks*16 + h*8;
    qh[ks] = ld8(&Qhi[g]); ql[ks] = ld8(&Qlo[g]);
  }

  auto computeS = [&](int t, f32x16& s){
    const u16* Kh = &SK[t&1][0][0];
    const u16* Kl = &SK[t&1][1][0];
    #pragma unroll
    for (int r=0;r<16;++r) s[r] = 0.f;
    #pragma unroll
    for (int ks=0;ks<8;++ks){
      int o = (ks*2+h)*256 + l31*8;
      bf16x8 ah = ld8(&Kh[o]);
      bf16x8 al = ld8(&Kl[o]);
      s = mfma32(ah, ql[ks], s);
      s = mfma32(al, qh[ks], s);
      s = mfma32(ah, qh[ks], s);
    }
  };

  f32x16 acc[4];
  #pragma unroll
  for (int mt=0;mt<4;++mt)
    #pragma unroll
    for (int r=0;r<16;++r) acc[mt][r] = 0.f;

  stageK(0); stageV(0); stageK(1);
  __syncthreads();
  f32x16 s;
  computeS(0, s);
  __syncthreads();

  for (int jt=0; jt<NJT; ++jt){
    const int cb = jt&1;
    if (jt+2 < NJT) stageK(jt+2);
    if (jt+1 < NJT) stageV(jt+1);

    float p[16];
    #pragma unroll
    for (int r=0;r<16;++r) p[r] = __expf(s[r]);

    if (jt+1 < NJT) computeS(jt+1, s);

    const u16* Vh = &SV[cb][0];
    #pragma unroll
    for (int t=0;t<2;++t){
      us8 fr = pfrag(&p[8*t], hb1);
      bf16x8 Bh; __builtin_memcpy(&Bh, &fr, 16);
      #pragma unroll
      for (int mt=0;mt<4;++mt){
        int o = (t*2+h)*1024 + (mt*32+l31)*8;
        bf16x8 vh = ld8(&Vh[o]);
        acc[mt] = mfma32(vh, Bh, acc[mt]);
      }
    }
    __syncthreads();
  }
  float* xp = out + (size_t)b*CH*NP;
  #pragma unroll
  for (int mt=0;mt<4;++mt){
    #pragma unroll
    for (int r=0;r<16;++r){
      int c = mt*32 + (r&3) + 8*(r>>2) + 4*h;
      atomicAdd(&xp[(size_t)c*NP + i0w + l31], acc[mt][r]);
    }
  }
}

extern "C" void kernel_launch(void* const* d_in, const int* in_sizes, int n_in,
                              void* d_out, int out_size, void* d_ws, size_t ws_size,
                              hipStream_t stream)
{
  const float* X  = (const float*)d_in[0];
  const float* Wq = (const float*)d_in[1];
  const float* bq = (const float*)d_in[2];
  const float* Wk = (const float*)d_in[3];
  const float* bk = (const float*)d_in[4];
  const float* Wv = (const float*)d_in[5];
  const float* bv = (const float*)d_in[6];
  float* outp = (float*)d_out;

  const size_t n = (size_t)NB*NP*CH;        // 2,097,152
  u16* Qhi = (u16*)d_ws;
  u16* Qlo = Qhi + n;
  u16* Khi = Qlo + n;
  u16* Klo = Khi + n;
  u16* Vthi = Klo + n;
  u16* Vtlo = Vthi + n;
  u16* Whi  = Vtlo + n;
  u16* Wlo  = Whi + 3*CH*CH;
  float* colpart = (float*)(Wlo + 3*CH*CH);      // ISPL*NB*NP floats
  u16* Pbuf = (u16*)(colpart + (size_t)ISPL*NB*NP);
  const size_t pelems = (size_t)NB*128*4*NP*8;   // 67,108,864 u16 = 128 MiB
  u16* Vfrag = Pbuf + pelems;                    // n u16 = 4 MiB
  u16* xpart = Vfrag + n;                        // JSPLP*n u16 = 32 MiB

  const size_t need = (size_t)((char*)xpart - (char*)d_ws)
                      + (size_t)JSPLP*n*sizeof(u16);
  const bool usep = (ws_size >= need);

  wsplit_kernel<<<dim3(CH*CH/256, 3),      256, 0, stream>>>(Wq, Wk, Wv, Whi, Wlo);
  proj_kernel  <<<dim3(NP/16, NB),          64, 0, stream>>>(X, Whi, Wlo, bq, bk, bv,
                                                             Qhi,Qlo, Khi,Klo, Vthi,Vtlo);
  if (usep){
    stats_kernel<true><<<dim3(NP/128, ISPL, NB), 256, 0, stream>>>(
        Qhi,Qlo, Khi,Klo, colpart, Pbuf);
    scalev_kernel<<<dim3(n/(256*8)),       256, 0, stream>>>(Vthi, Vtlo, colpart, Vfrag);
    attnp_kernel <<<dim3(NP/128, JSPLP, NB), 256, 0, stream>>>(Pbuf, Vfrag, xpart);
    final8_kernel<<<dim3(n/(256*4)),       256, 0, stream>>>(X, xpart, outp);
  } else {
    stats_kernel<false><<<dim3(NP/128, ISPL, NB), 256, 0, stream>>>(
        Qhi,Qlo, Khi,Klo, colpart, Pbuf);
    scalev_kernel<<<dim3(n/(256*8)),       256, 0, stream>>>(Vthi, Vtlo, colpart,
                                                             (u16*)nullptr);
    copyx_kernel <<<dim3(n/(256*4)),       256, 0, stream>>>(X, outp);
    attnf_kernel <<<dim3(NP/128, JSPLF, NB), 256, 0, stream>>>(
        Qhi,Qlo, Khi,Klo, Vthi, outp);
  }
}

// Round 18
// 223.969 us; speedup vs baseline: 1.0863x; 1.0107x over previous
//
#include <hip/hip_runtime.h>
#include <hip/hip_bf16.h>

// SelfAttention (B=4, C=128, H=W=64), fp32 I/O.
// out[b,c,i] = X[b,c,i] + sum_j exp(S[i,j]) * rinv_j * V[j,c],
//   S = Q K^T, rinv_j = 1/sum_i exp(S[i,j])   (softmax over query axis)
// S via split-bf16 (hi+lo) 3-term MFMA emulation (precision-critical).
// stats: LDS-shared Q staging (4-wave reuse), dbuf-pipelined, 64 j/wave
// (K frags x16 register-resident; each Q LDS read feeds 6 MFMAs), emits
// P=exp(S) in bf16 B-fragment image + column-sum partials.
// scalev: V' in A-fragment image. attnp: barrier-free LDS-free streaming
// P@V' GEMM, bf16 partials via plain stores (no atomics). final8 reduces.

typedef unsigned short u16;
typedef __attribute__((ext_vector_type(8))) __bf16 bf16x8;
typedef __attribute__((ext_vector_type(8))) unsigned short us8;
typedef __attribute__((ext_vector_type(4))) unsigned short us4;
typedef __attribute__((ext_vector_type(4))) float f32x4;
typedef __attribute__((ext_vector_type(16))) float f32x16;

#define NB 4
#define CH 128
#define NP 4096
#define ISPL 16   // stats i-splits
#define JSPLF 4   // fallback attn j-splits
#define JSPLP 8   // P-path attn j-splits

__device__ __forceinline__ float bf2f(u16 b){ union{float f;unsigned u;}v; v.u=((unsigned)b)<<16; return v.f; }
__device__ __forceinline__ u16 f2bf(float f){ union{float f;unsigned u;}v; v.f=f; unsigned r=v.u + 0x7FFFu + ((v.u>>16)&1u); return (u16)(r>>16); }

__device__ __forceinline__ f32x4 mfma16(bf16x8 a, bf16x8 b, f32x4 c){
  return __builtin_amdgcn_mfma_f32_16x16x32_bf16(a, b, c, 0, 0, 0);
}
__device__ __forceinline__ f32x16 mfma32(bf16x8 a, bf16x8 b, f32x16 c){
  return __builtin_amdgcn_mfma_f32_32x32x16_bf16(a, b, c, 0, 0, 0);
}
__device__ __forceinline__ bf16x8 ld8(const u16* p){
  union { us8 u; bf16x8 b; } v; v.u = *(const us8*)p; return v.b;
}
__device__ __forceinline__ void split8(const float* p, bf16x8& h, bf16x8& l){
  union { us8 u; bf16x8 b; } uh, ul;
  #pragma unroll
  for (int e=0;e<8;++e){
    float f = p[e];
    u16 hb = f2bf(f);
    uh.u[e] = hb;
    ul.u[e] = f2bf(f - bf2f(hb));
  }
  h = uh.b; l = ul.b;
}
__device__ __forceinline__ unsigned pk2(float a, float b){
  float2 f2; f2.x = a; f2.y = b;
  __hip_bfloat162 hb = __float22bfloat162_rn(f2);
  unsigned u; __builtin_memcpy(&u, &hb, 4);
  return u;
}
// C/D-layout p[8] (one k-tile) -> P^T B-fragment (lane n=i, k=h*8+e).
__device__ __forceinline__ us8 pfrag(const float* p, bool hb1){
  unsigned hA = pk2(p[0], p[1]);
  unsigned hB = pk2(p[2], p[3]);
  unsigned hC = pk2(p[4], p[5]);
  unsigned hD = pk2(p[6], p[7]);
  unsigned s0h = hb1? hA:hC, s1h = hb1? hB:hD;
  unsigned r0h = __shfl_xor(s0h, 32), r1h = __shfl_xor(s1h, 32);
  unsigned dh[4];
  dh[0] = hb1? r0h : hA;  dh[1] = hb1? r1h : hB;
  dh[2] = hb1? hC  : r0h; dh[3] = hb1? hD  : r1h;
  us8 o; __builtin_memcpy(&o, dh, 16); return o;
}
__device__ __forceinline__ void gll16(const void* g, void* l){
  __builtin_amdgcn_global_load_lds((const __attribute__((address_space(1))) void*)g,
                                   (__attribute__((address_space(3))) void*)l, 16, 0, 0);
}

// ---------------------------------------------------------------------------
// Kernel 0: pre-split the three 128x128 weight matrices into bf16 hi/lo.
// ---------------------------------------------------------------------------
__global__ __launch_bounds__(256) void wsplit_kernel(
    const float* __restrict__ Wq, const float* __restrict__ Wk,
    const float* __restrict__ Wv, u16* __restrict__ Whi, u16* __restrict__ Wlo)
{
  const int m = blockIdx.y;
  const float* W = (m==0) ? Wq : (m==1) ? Wk : Wv;
  int i = blockIdx.x*256 + threadIdx.x;
  float f = W[i];
  u16 hb = f2bf(f);
  Whi[m*CH*CH + i] = hb;
  Wlo[m*CH*CH + i] = f2bf(f - bf2f(hb));
}

// ---------------------------------------------------------------------------
// Kernel 1: projections (one wave per 16-pixel tile), 16x16x32 MFMA.
// ---------------------------------------------------------------------------
__global__ __launch_bounds__(64) void proj_kernel(
    const float* __restrict__ X,
    const u16* __restrict__ Whi, const u16* __restrict__ Wlo,
    const float* __restrict__ bq, const float* __restrict__ bk,
    const float* __restrict__ bv,
    u16* __restrict__ Qhi, u16* __restrict__ Qlo,
    u16* __restrict__ Khi, u16* __restrict__ Klo,
    u16* __restrict__ Vthi, u16* __restrict__ Vtlo)
{
  __shared__ float XT[16][CH+4];
  const int b = blockIdx.y, p0 = blockIdx.x*16, lane = threadIdx.x;
  #pragma unroll
  for (int h=0; h<2; ++h){
    int c = lane + h*64;
    const float* src = X + ((size_t)b*CH + c)*NP + p0;
    #pragma unroll
    for (int v4=0; v4<4; ++v4){
      f32x4 v = *(const f32x4*)(src + v4*4);
      #pragma unroll
      for (int p=0;p<4;++p) XT[v4*4+p][c] = v[p];
    }
  }
  __syncthreads();
  const int l15 = lane&15, quad = lane>>4;
  bf16x8 xh[4], xl[4];
  #pragma unroll
  for (int s=0;s<4;++s) split8(&XT[l15][s*32+quad*8], xh[s], xl[s]);

  const float* bm[2] = {bq, bk};
  u16* OH[2] = {Qhi, Khi};
  u16* OL[2] = {Qlo, Klo};
  #pragma unroll
  for (int m=0;m<2;++m){
    const u16* WH = Whi + m*CH*CH;
    const u16* WL = Wlo + m*CH*CH;
    #pragma unroll
    for (int nt=0;nt<8;++nt){
      f32x4 a = {0.f,0.f,0.f,0.f};
      #pragma unroll
      for (int s=0;s<4;++s){
        size_t g = (size_t)(nt*16+l15)*CH + s*32 + quad*8;
        bf16x8 wh = ld8(&WH[g]), wl = ld8(&WL[g]);
        a = mfma16(xh[s], wl, a);
        a = mfma16(xl[s], wh, a);
        a = mfma16(xh[s], wh, a);
      }
      int o = nt*16 + l15;
      float bias = bm[m][o];
      #pragma unroll
      for (int r=0;r<4;++r){
        int i = p0 + quad*4 + r;
        float q = a[r] + bias;
        u16 hb = f2bf(q);
        size_t idx = ((size_t)b*NP + i)*CH + o;
        OH[m][idx] = hb;
        OL[m][idx] = f2bf(q - bf2f(hb));
      }
    }
  }
  const u16* WH = Whi + 2*CH*CH;
  const u16* WL = Wlo + 2*CH*CH;
  #pragma unroll
  for (int mt=0;mt<8;++mt){
    f32x4 a = {0.f,0.f,0.f,0.f};
    #pragma unroll
    for (int s=0;s<4;++s){
      size_t g = (size_t)(mt*16+l15)*CH + s*32 + quad*8;
      bf16x8 wh = ld8(&WH[g]), wl = ld8(&WL[g]);
      a = mfma16(wh, xl[s], a);
      a = mfma16(wl, xh[s], a);
      a = mfma16(wh, xh[s], a);
    }
    #pragma unroll
    for (int r=0;r<4;++r){
      int co = mt*16 + quad*4 + r;
      float v = a[r] + bv[co];
      u16 hb = f2bf(v);
      size_t idx = ((size_t)b*CH + co)*NP + p0 + l15;
      Vthi[idx] = hb;
      Vtlo[idx] = f2bf(v - bf2f(hb));
    }
  }
}

// ---------------------------------------------------------------------------
// Kernel 2: S^T = K Q^T (32x32x16, 3-term), LDS-shared Q staging (dbuf,
// software-pipelined), 64 j per wave (two 32-j subtiles share each staged
// Q fragment: one LDS read feeds 6 MFMAs). Column sums always; if STOREP,
// also emit P=exp(S) as bf16 B-fragments to Pbuf[b][jtile][kh(4)][i]x16B.
// Grid (NP/256, ISPL, NB).
// ---------------------------------------------------------------------------
template<bool STOREP>
__global__ __launch_bounds__(256,2) void stats_kernel(
    const u16* __restrict__ Qhi, const u16* __restrict__ Qlo,
    const u16* __restrict__ Khi, const u16* __restrict__ Klo,
    float* __restrict__ colpart, u16* __restrict__ Pbuf)
{
  __shared__ u16 SQ[2][2][32*CH];
  const int b = blockIdx.z, isplit = blockIdx.y;
  const int tid = threadIdx.x, lane = tid&63, w = tid>>6;
  const int l31 = lane&31, h = lane>>5;
  const int j0w = blockIdx.x*256 + w*64;
  const bool hb1 = (h != 0);

  const int slot0 = w*128 + lane, slot1 = slot0 + 64;
  const int qr0 = slot0&31, qc0 = slot0>>5, qr1 = slot1&31, qc1 = slot1>>5;
  const size_t qg0 = ((size_t)b*NP + qr0)*CH + qc0*8;
  const size_t qg1 = ((size_t)b*NP + qr1)*CH + qc1*8;
  const int lof0 = slot0*8, lof1 = slot1*8;

  // K fragments for two 32-j subtiles: A[m=j][k], register-resident
  bf16x8 kh[16], kl[16];
  #pragma unroll
  for (int sub=0;sub<2;++sub)
    #pragma unroll
    for (int ks=0;ks<8;++ks){
      size_t g = ((size_t)b*NP + j0w + sub*32 + l31)*CH + ks*16 + h*8;
      kh[sub*8+ks] = ld8(&Khi[g]);
      kl[sub*8+ks] = ld8(&Klo[g]);
    }

  const int ibase = isplit*(NP/ISPL);
  const int NCH = (NP/ISPL)/32;     // 8 chunks
  const int jt0 = blockIdx.x*8 + w*2;   // first of this wave's two j-tiles
  const size_t Pjt0 = ((size_t)(b*128 + jt0))*((size_t)4*NP*8);
  const size_t Pjt1 = ((size_t)(b*128 + jt0 + 1))*((size_t)4*NP*8);

  auto stageQ = [&](int t){
    size_t iofs = (size_t)(ibase + t*32)*CH;
    int bf = t&1;
    gll16(&Qhi[qg0 + iofs], &SQ[bf][0][lof0]);
    gll16(&Qhi[qg1 + iofs], &SQ[bf][0][lof1]);
    gll16(&Qlo[qg0 + iofs], &SQ[bf][1][lof0]);
    gll16(&Qlo[qg1 + iofs], &SQ[bf][1][lof1]);
  };
  auto computeS2 = [&](int t, f32x16& s0, f32x16& s1){
    const u16* Qh = &SQ[t&1][0][0];
    const u16* Ql = &SQ[t&1][1][0];
    #pragma unroll
    for (int r=0;r<16;++r){ s0[r] = 0.f; s1[r] = 0.f; }
    #pragma unroll
    for (int ks=0;ks<8;++ks){
      int o = (ks*2+h)*256 + l31*8;
      bf16x8 qbh = ld8(&Qh[o]);
      bf16x8 qbl = ld8(&Ql[o]);
      s0 = mfma32(kh[ks],   qbl, s0);
      s1 = mfma32(kh[8+ks], qbl, s1);
      s0 = mfma32(kl[ks],   qbh, s0);
      s1 = mfma32(kl[8+ks], qbh, s1);
      s0 = mfma32(kh[ks],   qbh, s0);
      s1 = mfma32(kh[8+ks], qbh, s1);
    }
  };

  stageQ(0); if (NCH > 1) stageQ(1);
  __syncthreads();
  f32x16 s0, s1;
  computeS2(0, s0, s1);
  __syncthreads();

  float scol0[16], scol1[16];
  #pragma unroll
  for (int r=0;r<16;++r){ scol0[r] = 0.f; scol1[r] = 0.f; }

  for (int ic=0; ic<NCH; ++ic){
    if (ic+2 < NCH) stageQ(ic+2);
    float p0[16], p1[16];
    #pragma unroll
    for (int r=0;r<16;++r){
      p0[r] = __expf(s0[r]); scol0[r] += p0[r];
      p1[r] = __expf(s1[r]); scol1[r] += p1[r];
    }
    if (STOREP){
      int iglob = ibase + ic*32 + l31;
      #pragma unroll
      for (int t=0;t<2;++t){
        us8 f0 = pfrag(&p0[8*t], hb1);
        *(us8*)&Pbuf[Pjt0 + ((size_t)((t*2+h)*NP) + iglob)*8] = f0;
        us8 f1 = pfrag(&p1[8*t], hb1);
        *(us8*)&Pbuf[Pjt1 + ((size_t)((t*2+h)*NP) + iglob)*8] = f1;
      }
    }
    if (ic+1 < NCH) computeS2(ic+1, s0, s1);
    __syncthreads();
  }
  #pragma unroll
  for (int m=1; m<32; m<<=1){
    #pragma unroll
    for (int r=0;r<16;++r){
      scol0[r] += __shfl_xor(scol0[r], m);
      scol1[r] += __shfl_xor(scol1[r], m);
    }
  }
  if (l31 == 0){
    #pragma unroll
    for (int r=0;r<16;++r){
      int jo = (r&3) + 8*(r>>2) + 4*h;
      colpart[((size_t)(isplit*NB + b))*NP + j0w + jo] = scol0[r];
      colpart[((size_t)(isplit*NB + b))*NP + j0w + 32 + jo] = scol1[r];
    }
  }
}

// ---------------------------------------------------------------------------
// Kernel 3: V' = rinv_j * V -> bf16: in-place hi (for fallback) AND, when
// Vfrag != nullptr, the A-fragment image Vfrag[b][jtile][kchunk(4)][c(128)]x8.
// ---------------------------------------------------------------------------
__global__ __launch_bounds__(256) void scalev_kernel(
    u16* __restrict__ Vthi, const u16* __restrict__ Vtlo,
    const float* __restrict__ colpart, u16* __restrict__ Vfrag)
{
  size_t t = (size_t)blockIdx.x*256 + threadIdx.x;
  size_t base = t*8;
  int bc = (int)(base >> 12);
  int b  = bc >> 7;
  int c  = bc & 127;
  int j0 = (int)(base & (NP-1));
  f32x4 s0 = {0.f,0.f,0.f,0.f}, s1 = {0.f,0.f,0.f,0.f};
  #pragma unroll
  for (int k=0;k<ISPL;++k){
    const float* cp = &colpart[((size_t)(k*NB + b))*NP + j0];
    f32x4 a0 = *(const f32x4*)cp;
    f32x4 a1 = *(const f32x4*)(cp+4);
    #pragma unroll
    for (int e=0;e<4;++e){ s0[e]+=a0[e]; s1[e]+=a1[e]; }
  }
  us8 hh = *(const us8*)&Vthi[base];
  us8 ll = *(const us8*)&Vtlo[base];
  us8 oh;
  #pragma unroll
  for (int e=0;e<8;++e){
    float r = 1.0f / (e<4 ? s0[e] : s1[e-4]);
    float v = (bf2f(hh[e]) + bf2f(ll[e])) * r;
    oh[e] = f2bf(v);
  }
  *(us8*)&Vthi[base] = oh;
  if (Vfrag){
    int jt = j0 >> 5;
    int kc = ((j0 >> 4) & 1)*2 + ((j0 >> 3) & 1);
    size_t o = (((size_t)(b*128 + jt))*4 + kc)*((size_t)CH*8) + (size_t)c*8;
    *(us8*)&Vfrag[o] = oh;
  }
}

// ---------------------------------------------------------------------------
// Kernel 4: out := X   (fallback path seed only)
// ---------------------------------------------------------------------------
__global__ __launch_bounds__(256) void copyx_kernel(
    const float* __restrict__ X, float* __restrict__ out)
{
  size_t idx = ((size_t)blockIdx.x*256 + threadIdx.x)*4;
  *(f32x4*)&out[idx] = *(const f32x4*)&X[idx];
}

// ---------------------------------------------------------------------------
// Kernel 5a (P path): barrier-free, LDS-free streaming P@V'.
// Both operands are fragment-image arrays (all loads coalesced 16B/lane).
// Partials stored as bf16 (plain stores, no atomics).
// ---------------------------------------------------------------------------
__global__ __launch_bounds__(256,4) void attnp_kernel(
    const u16* __restrict__ Pbuf, const u16* __restrict__ Vfrag,
    u16* __restrict__ xpart)
{
  const int b = blockIdx.z, jsplit = blockIdx.y;
  const int tid = threadIdx.x, lane = tid&63, w = tid>>6;
  const int l31 = lane&31, h = lane>>5;
  const int i0w = blockIdx.x*128 + w*32;

  const int NJT = (NP/JSPLP)/32;   // 16 j-tiles of 32

  f32x16 acc[4];
  #pragma unroll
  for (int mt=0;mt<4;++mt)
    #pragma unroll
    for (int r=0;r<16;++r) acc[mt][r] = 0.f;

  for (int jt=0; jt<NJT; ++jt){
    const int jtg = jsplit*NJT + jt;               // global j-tile 0..127
    const size_t Pjt = ((size_t)(b*128 + jtg))*((size_t)4*NP*8);
    const size_t Vjt = ((size_t)(b*128 + jtg))*((size_t)4*CH*8);
    #pragma unroll
    for (int t=0;t<2;++t){
      bf16x8 Bh = ld8(&Pbuf[Pjt + ((size_t)((t*2+h)*NP) + i0w + l31)*8]);
      #pragma unroll
      for (int mt=0;mt<4;++mt){
        bf16x8 vh = ld8(&Vfrag[Vjt + (size_t)((t*2+h)*CH + mt*32 + l31)*8]);
        acc[mt] = mfma32(vh, Bh, acc[mt]);
      }
    }
  }
  u16* xp = xpart + ((size_t)(jsplit*NB + b))*(size_t)CH*NP;
  #pragma unroll
  for (int mt=0;mt<4;++mt){
    #pragma unroll
    for (int r=0;r<16;++r){
      int c = mt*32 + (r&3) + 8*(r>>2) + 4*h;
      xp[(size_t)c*NP + i0w + l31] = f2bf(acc[mt][r]);
    }
  }
}

// ---------------------------------------------------------------------------
// Kernel 5a': out = X + sum_{k<JSPLP} bf2f(xpart[k])
// ---------------------------------------------------------------------------
__global__ __launch_bounds__(256) void final8_kernel(
    const float* __restrict__ X, const u16* __restrict__ xpart,
    float* __restrict__ out)
{
  const size_t n = (size_t)NB*CH*NP;
  size_t idx = ((size_t)blockIdx.x*256 + threadIdx.x)*4;
  f32x4 s = *(const f32x4*)&X[idx];
  #pragma unroll
  for (int k=0;k<JSPLP;++k){
    us4 p = *(const us4*)&xpart[(size_t)k*n + idx];
    #pragma unroll
    for (int e=0;e<4;++e) s[e] += bf2f(p[e]);
  }
  *(f32x4*)&out[idx] = s;
}

// ---------------------------------------------------------------------------
// Kernel 5b (fallback, ws too small): flash attn (atomics into out).
// ---------------------------------------------------------------------------
__global__ __launch_bounds__(256,2) void attnf_kernel(
    const u16* __restrict__ Qhi, const u16* __restrict__ Qlo,
    const u16* __restrict__ Khi, const u16* __restrict__ Klo,
    const u16* __restrict__ Vthi,
    float* __restrict__ out)
{
  __shared__ u16 SK[2][2][32*CH];
  __shared__ u16 SV[2][4*CH*8];
  const int b = blockIdx.z, jsplit = blockIdx.y;
  const int tid = threadIdx.x, lane = tid&63, w = tid>>6;
  const int l31 = lane&31, h = lane>>5;
  const int i0w = blockIdx.x*128 + w*32;
  const bool hb1 = (h != 0);

  const int slot0 = tid, slot1 = tid + 256;
  const int kr0 = slot0&31, kc0 = slot0>>5, kr1 = slot1&31, kc1 = slot1>>5;
  const size_t kg0 = ((size_t)b*NP + kr0)*CH + kc0*8;
  const size_t kg1 = ((size_t)b*NP + kr1)*CH + kc1*8;
  const size_t vg0 = ((size_t)b*CH + (slot0&127))*NP + (slot0>>7)*8;
  const size_t vg1 = ((size_t)b*CH + (slot1&127))*NP + (slot1>>7)*8;
  const int lof0 = slot0*8, lof1 = slot1*8;

  const int jbase = jsplit*(NP/JSPLF);
  const int NJT = (NP/JSPLF)/32;

  auto stageK = [&](int t){
    size_t jofs = (size_t)(jbase + t*32)*CH;
    int bf = t&1;
    gll16(&Khi[kg0 + jofs], &SK[bf][0][lof0]);
    gll16(&Khi[kg1 + jofs], &SK[bf][0][lof1]);
    gll16(&Klo[kg0 + jofs], &SK[bf][1][lof0]);
    gll16(&Klo[kg1 + jofs], &SK[bf][1][lof1]);
  };
  auto stageV = [&](int t){
    int j0 = jbase + t*32;
    int bf = t&1;
    gll16(&Vthi[vg0 + j0], &SV[bf][lof0]);
    gll16(&Vthi[vg1 + j0], &SV[bf][lof1]);
  };

  bf16x8 qh[8], ql[8];
  #pragma unroll
  for (int ks=0;ks<8;++ks){
    size_t g = ((size_t)b*NP + i0w + l31)*CH + ks*16 + h*8;
    qh[ks] = ld8(&Qhi[g]); ql[ks] = ld8(&Qlo[g]);
  }

  auto computeS = [&](int t, f32x16& s){
    const u16* Kh = &SK[t&1][0][0];
    const u16* Kl = &SK[t&1][1][0];
    #pragma unroll
    for (int r=0;r<16;++r) s[r] = 0.f;
    #pragma unroll
    for (int ks=0;ks<8;++ks){
      int o = (ks*2+h)*256 + l31*8;
      bf16x8 ah = ld8(&Kh[o]);
      bf16x8 al = ld8(&Kl[o]);
      s = mfma32(ah, ql[ks], s);
      s = mfma32(al, qh[ks], s);
      s = mfma32(ah, qh[ks], s);
    }
  };

  f32x16 acc[4];
  #pragma unroll
  for (int mt=0;mt<4;++mt)
    #pragma unroll
    for (int r=0;r<16;++r) acc[mt][r] = 0.f;

  stageK(0); stageV(0); stageK(1);
  __syncthreads();
  f32x16 s;
  computeS(0, s);
  __syncthreads();

  for (int jt=0; jt<NJT; ++jt){
    const int cb = jt&1;
    if (jt+2 < NJT) stageK(jt+2);
    if (jt+1 < NJT) stageV(jt+1);

    float p[16];
    #pragma unroll
    for (int r=0;r<16;++r) p[r] = __expf(s[r]);

    if (jt+1 < NJT) computeS(jt+1, s);

    const u16* Vh = &SV[cb][0];
    #pragma unroll
    for (int t=0;t<2;++t){
      us8 fr = pfrag(&p[8*t], hb1);
      bf16x8 Bh; __builtin_memcpy(&Bh, &fr, 16);
      #pragma unroll
      for (int mt=0;mt<4;++mt){
        int o = (t*2+h)*1024 + (mt*32+l31)*8;
        bf16x8 vh = ld8(&Vh[o]);
        acc[mt] = mfma32(vh, Bh, acc[mt]);
      }
    }
    __syncthreads();
  }
  float* xp = out + (size_t)b*CH*NP;
  #pragma unroll
  for (int mt=0;mt<4;++mt){
    #pragma unroll
    for (int r=0;r<16;++r){
      int c = mt*32 + (r&3) + 8*(r>>2) + 4*h;
      atomicAdd(&xp[(size_t)c*NP + i0w + l31], acc[mt][r]);
    }
  }
}

extern "C" void kernel_launch(void* const* d_in, const int* in_sizes, int n_in,
                              void* d_out, int out_size, void* d_ws, size_t ws_size,
                              hipStream_t stream)
{
  const float* X  = (const float*)d_in[0];
  const float* Wq = (const float*)d_in[1];
  const float* bq = (const float*)d_in[2];
  const float* Wk = (const float*)d_in[3];
  const float* bk = (const float*)d_in[4];
  const float* Wv = (const float*)d_in[5];
  const float* bv = (const float*)d_in[6];
  float* outp = (float*)d_out;

  const size_t n = (size_t)NB*NP*CH;        // 2,097,152
  u16* Qhi = (u16*)d_ws;
  u16* Qlo = Qhi + n;
  u16* Khi = Qlo + n;
  u16* Klo = Khi + n;
  u16* Vthi = Klo + n;
  u16* Vtlo = Vthi + n;
  u16* Whi  = Vtlo + n;
  u16* Wlo  = Whi + 3*CH*CH;
  float* colpart = (float*)(Wlo + 3*CH*CH);      // ISPL*NB*NP floats
  u16* Pbuf = (u16*)(colpart + (size_t)ISPL*NB*NP);
  const size_t pelems = (size_t)NB*128*4*NP*8;   // 67,108,864 u16 = 128 MiB
  u16* Vfrag = Pbuf + pelems;                    // n u16 = 4 MiB
  u16* xpart = Vfrag + n;                        // JSPLP*n u16 = 32 MiB

  const size_t need = (size_t)((char*)xpart - (char*)d_ws)
                      + (size_t)JSPLP*n*sizeof(u16);
  const bool usep = (ws_size >= need);

  wsplit_kernel<<<dim3(CH*CH/256, 3),      256, 0, stream>>>(Wq, Wk, Wv, Whi, Wlo);
  proj_kernel  <<<dim3(NP/16, NB),          64, 0, stream>>>(X, Whi, Wlo, bq, bk, bv,
                                                             Qhi,Qlo, Khi,Klo, Vthi,Vtlo);
  if (usep){
    stats_kernel<true><<<dim3(NP/256, ISPL, NB), 256, 0, stream>>>(
        Qhi,Qlo, Khi,Klo, colpart, Pbuf);
    scalev_kernel<<<dim3(n/(256*8)),       256, 0, stream>>>(Vthi, Vtlo, colpart, Vfrag);
    attnp_kernel <<<dim3(NP/128, JSPLP, NB), 256, 0, stream>>>(Pbuf, Vfrag, xpart);
    final8_kernel<<<dim3(n/(256*4)),       256, 0, stream>>>(X, xpart, outp);
  } else {
    stats_kernel<false><<<dim3(NP/256, ISPL, NB), 256, 0, stream>>>(
        Qhi,Qlo, Khi,Klo, colpart, Pbuf);
    scalev_kernel<<<dim3(n/(256*8)),       256, 0, stream>>>(Vthi, Vtlo, colpart,
                                                             (u16*)nullptr);
    copyx_kernel <<<dim3(n/(256*4)),       256, 0, stream>>>(X, outp);
    attnf_kernel <<<dim3(NP/128, JSPLF, NB), 256, 0, stream>>>(
        Qhi,Qlo, Khi,Klo, Vthi, outp);
  }
}

// Round 19
// 222.036 us; speedup vs baseline: 1.0958x; 1.0087x over previous
//
#include <hip/hip_runtime.h>
#include <hip/hip_bf16.h>

// SelfAttention (B=4, C=128, H=W=64), fp32 I/O.
// out[b,c,i] = X[b,c,i] + sum_j exp(S[i,j]) * rinv_j * V[j,c],
//   S = Q K^T, rinv_j = 1/sum_i exp(S[i,j])   (softmax over query axis)
// S via split-bf16 (hi+lo) 3-term MFMA emulation (precision-critical).
// proj: 4 waves/block sharing one LDS X-tile (16 waves/CU).
// stats: LDS-shared Q staging (4-wave reuse), dbuf-pipelined, 32 j/wave,
// emits P=exp(S) in bf16 B-fragment image + column-sum partials.
// scalev: V' in A-fragment image. attnp: barrier-free LDS-free streaming
// P@V' GEMM, bf16 partials via plain stores (no atomics). final8 reduces.

typedef unsigned short u16;
typedef __attribute__((ext_vector_type(8))) __bf16 bf16x8;
typedef __attribute__((ext_vector_type(8))) unsigned short us8;
typedef __attribute__((ext_vector_type(4))) unsigned short us4;
typedef __attribute__((ext_vector_type(4))) float f32x4;
typedef __attribute__((ext_vector_type(16))) float f32x16;

#define NB 4
#define CH 128
#define NP 4096
#define ISPL 16   // stats i-splits
#define JSPLF 4   // fallback attn j-splits
#define JSPLP 8   // P-path attn j-splits

__device__ __forceinline__ float bf2f(u16 b){ union{float f;unsigned u;}v; v.u=((unsigned)b)<<16; return v.f; }
__device__ __forceinline__ u16 f2bf(float f){ union{float f;unsigned u;}v; v.f=f; unsigned r=v.u + 0x7FFFu + ((v.u>>16)&1u); return (u16)(r>>16); }

__device__ __forceinline__ f32x4 mfma16(bf16x8 a, bf16x8 b, f32x4 c){
  return __builtin_amdgcn_mfma_f32_16x16x32_bf16(a, b, c, 0, 0, 0);
}
__device__ __forceinline__ f32x16 mfma32(bf16x8 a, bf16x8 b, f32x16 c){
  return __builtin_amdgcn_mfma_f32_32x32x16_bf16(a, b, c, 0, 0, 0);
}
__device__ __forceinline__ bf16x8 ld8(const u16* p){
  union { us8 u; bf16x8 b; } v; v.u = *(const us8*)p; return v.b;
}
__device__ __forceinline__ void split8(const float* p, bf16x8& h, bf16x8& l){
  union { us8 u; bf16x8 b; } uh, ul;
  #pragma unroll
  for (int e=0;e<8;++e){
    float f = p[e];
    u16 hb = f2bf(f);
    uh.u[e] = hb;
    ul.u[e] = f2bf(f - bf2f(hb));
  }
  h = uh.b; l = ul.b;
}
__device__ __forceinline__ unsigned pk2(float a, float b){
  float2 f2; f2.x = a; f2.y = b;
  __hip_bfloat162 hb = __float22bfloat162_rn(f2);
  unsigned u; __builtin_memcpy(&u, &hb, 4);
  return u;
}
// C/D-layout p[8] (one k-tile) -> P^T B-fragment (lane n=i, k=h*8+e).
__device__ __forceinline__ us8 pfrag(const float* p, bool hb1){
  unsigned hA = pk2(p[0], p[1]);
  unsigned hB = pk2(p[2], p[3]);
  unsigned hC = pk2(p[4], p[5]);
  unsigned hD = pk2(p[6], p[7]);
  unsigned s0h = hb1? hA:hC, s1h = hb1? hB:hD;
  unsigned r0h = __shfl_xor(s0h, 32), r1h = __shfl_xor(s1h, 32);
  unsigned dh[4];
  dh[0] = hb1? r0h : hA;  dh[1] = hb1? r1h : hB;
  dh[2] = hb1? hC  : r0h; dh[3] = hb1? hD  : r1h;
  us8 o; __builtin_memcpy(&o, dh, 16); return o;
}
__device__ __forceinline__ void gll16(const void* g, void* l){
  __builtin_amdgcn_global_load_lds((const __attribute__((address_space(1))) void*)g,
                                   (__attribute__((address_space(3))) void*)l, 16, 0, 0);
}

// ---------------------------------------------------------------------------
// Kernel 0: pre-split the three 128x128 weight matrices into bf16 hi/lo.
// ---------------------------------------------------------------------------
__global__ __launch_bounds__(256) void wsplit_kernel(
    const float* __restrict__ Wq, const float* __restrict__ Wk,
    const float* __restrict__ Wv, u16* __restrict__ Whi, u16* __restrict__ Wlo)
{
  const int m = blockIdx.y;
  const float* W = (m==0) ? Wq : (m==1) ? Wk : Wv;
  int i = blockIdx.x*256 + threadIdx.x;
  float f = W[i];
  u16 hb = f2bf(f);
  Whi[m*CH*CH + i] = hb;
  Wlo[m*CH*CH + i] = f2bf(f - bf2f(hb));
}

// ---------------------------------------------------------------------------
// Kernel 1: projections. 256-thread blocks: 4 waves share one 16-pixel
// X-tile in LDS; wave w computes nt {2w,2w+1} of Q and K, mt {2w,2w+1} of V.
// ---------------------------------------------------------------------------
__global__ __launch_bounds__(256) void proj_kernel(
    const float* __restrict__ X,
    const u16* __restrict__ Whi, const u16* __restrict__ Wlo,
    const float* __restrict__ bq, const float* __restrict__ bk,
    const float* __restrict__ bv,
    u16* __restrict__ Qhi, u16* __restrict__ Qlo,
    u16* __restrict__ Khi, u16* __restrict__ Klo,
    u16* __restrict__ Vthi, u16* __restrict__ Vtlo)
{
  __shared__ float XT[16][CH+4];
  const int b = blockIdx.y, p0 = blockIdx.x*16;
  const int tid = threadIdx.x, lane = tid&63, w = tid>>6;
  {
    int c = tid & 127, half = tid >> 7;
    const float* src = X + ((size_t)b*CH + c)*NP + p0 + half*8;
    f32x4 v0 = *(const f32x4*)src;
    f32x4 v1 = *(const f32x4*)(src + 4);
    #pragma unroll
    for (int p=0;p<4;++p) XT[half*8 + p][c] = v0[p];
    #pragma unroll
    for (int p=0;p<4;++p) XT[half*8 + 4 + p][c] = v1[p];
  }
  __syncthreads();
  const int l15 = lane&15, quad = lane>>4;
  bf16x8 xh[4], xl[4];
  #pragma unroll
  for (int s=0;s<4;++s) split8(&XT[l15][s*32+quad*8], xh[s], xl[s]);

  const float* bm[2] = {bq, bk};
  u16* OH[2] = {Qhi, Khi};
  u16* OL[2] = {Qlo, Klo};
  #pragma unroll
  for (int m=0;m<2;++m){
    const u16* WH = Whi + m*CH*CH;
    const u16* WL = Wlo + m*CH*CH;
    #pragma unroll
    for (int nn=0;nn<2;++nn){
      int nt = w*2 + nn;
      f32x4 a = {0.f,0.f,0.f,0.f};
      #pragma unroll
      for (int s=0;s<4;++s){
        size_t g = (size_t)(nt*16+l15)*CH + s*32 + quad*8;
        bf16x8 wh = ld8(&WH[g]), wl = ld8(&WL[g]);
        a = mfma16(xh[s], wl, a);
        a = mfma16(xl[s], wh, a);
        a = mfma16(xh[s], wh, a);
      }
      int o = nt*16 + l15;
      float bias = bm[m][o];
      #pragma unroll
      for (int r=0;r<4;++r){
        int i = p0 + quad*4 + r;
        float q = a[r] + bias;
        u16 hb = f2bf(q);
        size_t idx = ((size_t)b*NP + i)*CH + o;
        OH[m][idx] = hb;
        OL[m][idx] = f2bf(q - bf2f(hb));
      }
    }
  }
  const u16* WH = Whi + 2*CH*CH;
  const u16* WL = Wlo + 2*CH*CH;
  #pragma unroll
  for (int mm=0;mm<2;++mm){
    int mt = w*2 + mm;
    f32x4 a = {0.f,0.f,0.f,0.f};
    #pragma unroll
    for (int s=0;s<4;++s){
      size_t g = (size_t)(mt*16+l15)*CH + s*32 + quad*8;
      bf16x8 wh = ld8(&WH[g]), wl = ld8(&WL[g]);
      a = mfma16(wh, xl[s], a);
      a = mfma16(wl, xh[s], a);
      a = mfma16(wh, xh[s], a);
    }
    #pragma unroll
    for (int r=0;r<4;++r){
      int co = mt*16 + quad*4 + r;
      float v = a[r] + bv[co];
      u16 hb = f2bf(v);
      size_t idx = ((size_t)b*CH + co)*NP + p0 + l15;
      Vthi[idx] = hb;
      Vtlo[idx] = f2bf(v - bf2f(hb));
    }
  }
}

// ---------------------------------------------------------------------------
// Kernel 2: S^T = K Q^T (32x32x16, 3-term), LDS-shared Q staging (dbuf,
// software-pipelined), 32 j per wave. Column sums always; if STOREP, also
// emit P=exp(S) as bf16 B-fragments to Pbuf[b][jtile][kh(4)][i(4096)]x16B.
// ---------------------------------------------------------------------------
template<bool STOREP>
__global__ __launch_bounds__(256,3) void stats_kernel(
    const u16* __restrict__ Qhi, const u16* __restrict__ Qlo,
    const u16* __restrict__ Khi, const u16* __restrict__ Klo,
    float* __restrict__ colpart, u16* __restrict__ Pbuf)
{
  __shared__ u16 SQ[2][2][32*CH];
  const int b = blockIdx.z, isplit = blockIdx.y;
  const int tid = threadIdx.x, lane = tid&63, w = tid>>6;
  const int l31 = lane&31, h = lane>>5;
  const int j0w = blockIdx.x*128 + w*32;
  const bool hb1 = (h != 0);

  const int slot0 = w*128 + lane, slot1 = slot0 + 64;
  const int qr0 = slot0&31, qc0 = slot0>>5, qr1 = slot1&31, qc1 = slot1>>5;
  const size_t qg0 = ((size_t)b*NP + qr0)*CH + qc0*8;
  const size_t qg1 = ((size_t)b*NP + qr1)*CH + qc1*8;
  const int lof0 = slot0*8, lof1 = slot1*8;

  bf16x8 kh[8], kl[8];
  #pragma unroll
  for (int ks=0;ks<8;++ks){
    size_t g = ((size_t)b*NP + j0w + l31)*CH + ks*16 + h*8;
    kh[ks] = ld8(&Khi[g]);
    kl[ks] = ld8(&Klo[g]);
  }

  const int ibase = isplit*(NP/ISPL);
  const int NCH = (NP/ISPL)/32;     // 8 chunks
  const size_t Pjt = ((size_t)(b*128 + blockIdx.x*4 + w))*((size_t)4*NP*8);

  auto stageQ = [&](int t){
    size_t iofs = (size_t)(ibase + t*32)*CH;
    int bf = t&1;
    gll16(&Qhi[qg0 + iofs], &SQ[bf][0][lof0]);
    gll16(&Qhi[qg1 + iofs], &SQ[bf][0][lof1]);
    gll16(&Qlo[qg0 + iofs], &SQ[bf][1][lof0]);
    gll16(&Qlo[qg1 + iofs], &SQ[bf][1][lof1]);
  };
  auto computeS = [&](int t, f32x16& s){
    const u16* Qh = &SQ[t&1][0][0];
    const u16* Ql = &SQ[t&1][1][0];
    #pragma unroll
    for (int r=0;r<16;++r) s[r] = 0.f;
    #pragma unroll
    for (int ks=0;ks<8;++ks){
      int o = (ks*2+h)*256 + l31*8;
      bf16x8 qbh = ld8(&Qh[o]);
      bf16x8 qbl = ld8(&Ql[o]);
      s = mfma32(kh[ks], qbl, s);
      s = mfma32(kl[ks], qbh, s);
      s = mfma32(kh[ks], qbh, s);
    }
  };

  stageQ(0); if (NCH > 1) stageQ(1);
  __syncthreads();
  f32x16 s;
  computeS(0, s);
  __syncthreads();

  float scol[16];
  #pragma unroll
  for (int r=0;r<16;++r) scol[r] = 0.f;

  for (int ic=0; ic<NCH; ++ic){
    if (ic+2 < NCH) stageQ(ic+2);
    float p[16];
    #pragma unroll
    for (int r=0;r<16;++r){ p[r] = __expf(s[r]); scol[r] += p[r]; }
    if (STOREP){
      int iglob = ibase + ic*32 + l31;
      #pragma unroll
      for (int t=0;t<2;++t){
        us8 frag = pfrag(&p[8*t], hb1);
        *(us8*)&Pbuf[Pjt + ((size_t)((t*2+h)*NP) + iglob)*8] = frag;
      }
    }
    if (ic+1 < NCH) computeS(ic+1, s);
    __syncthreads();
  }
  #pragma unroll
  for (int m=1; m<32; m<<=1){
    #pragma unroll
    for (int r=0;r<16;++r) scol[r] += __shfl_xor(scol[r], m);
  }
  if (l31 == 0){
    #pragma unroll
    for (int r=0;r<16;++r){
      int j = j0w + (r&3) + 8*(r>>2) + 4*h;
      colpart[((size_t)(isplit*NB + b))*NP + j] = scol[r];
    }
  }
}

// ---------------------------------------------------------------------------
// Kernel 3: V' = rinv_j * V -> bf16: in-place hi (for fallback) AND, when
// Vfrag != nullptr, the A-fragment image Vfrag[b][jtile][kchunk(4)][c(128)]x8.
// ---------------------------------------------------------------------------
__global__ __launch_bounds__(256) void scalev_kernel(
    u16* __restrict__ Vthi, const u16* __restrict__ Vtlo,
    const float* __restrict__ colpart, u16* __restrict__ Vfrag)
{
  size_t t = (size_t)blockIdx.x*256 + threadIdx.x;
  size_t base = t*8;
  int bc = (int)(base >> 12);
  int b  = bc >> 7;
  int c  = bc & 127;
  int j0 = (int)(base & (NP-1));
  f32x4 s0 = {0.f,0.f,0.f,0.f}, s1 = {0.f,0.f,0.f,0.f};
  #pragma unroll
  for (int k=0;k<ISPL;++k){
    const float* cp = &colpart[((size_t)(k*NB + b))*NP + j0];
    f32x4 a0 = *(const f32x4*)cp;
    f32x4 a1 = *(const f32x4*)(cp+4);
    #pragma unroll
    for (int e=0;e<4;++e){ s0[e]+=a0[e]; s1[e]+=a1[e]; }
  }
  us8 hh = *(const us8*)&Vthi[base];
  us8 ll = *(const us8*)&Vtlo[base];
  us8 oh;
  #pragma unroll
  for (int e=0;e<8;++e){
    float r = 1.0f / (e<4 ? s0[e] : s1[e-4]);
    float v = (bf2f(hh[e]) + bf2f(ll[e])) * r;
    oh[e] = f2bf(v);
  }
  *(us8*)&Vthi[base] = oh;
  if (Vfrag){
    int jt = j0 >> 5;
    int kc = ((j0 >> 4) & 1)*2 + ((j0 >> 3) & 1);
    size_t o = (((size_t)(b*128 + jt))*4 + kc)*((size_t)CH*8) + (size_t)c*8;
    *(us8*)&Vfrag[o] = oh;
  }
}

// ---------------------------------------------------------------------------
// Kernel 4: out := X   (fallback path seed only)
// ---------------------------------------------------------------------------
__global__ __launch_bounds__(256) void copyx_kernel(
    const float* __restrict__ X, float* __restrict__ out)
{
  size_t idx = ((size_t)blockIdx.x*256 + threadIdx.x)*4;
  *(f32x4*)&out[idx] = *(const f32x4*)&X[idx];
}

// ---------------------------------------------------------------------------
// Kernel 5a (P path): barrier-free, LDS-free streaming P@V'.
// Both operands are fragment-image arrays (all loads coalesced 16B/lane).
// Partials stored as bf16 (plain stores, no atomics).
// ---------------------------------------------------------------------------
__global__ __launch_bounds__(256,4) void attnp_kernel(
    const u16* __restrict__ Pbuf, const u16* __restrict__ Vfrag,
    u16* __restrict__ xpart)
{
  const int b = blockIdx.z, jsplit = blockIdx.y;
  const int tid = threadIdx.x, lane = tid&63, w = tid>>6;
  const int l31 = lane&31, h = lane>>5;
  const int i0w = blockIdx.x*128 + w*32;

  const int NJT = (NP/JSPLP)/32;   // 16 j-tiles of 32

  f32x16 acc[4];
  #pragma unroll
  for (int mt=0;mt<4;++mt)
    #pragma unroll
    for (int r=0;r<16;++r) acc[mt][r] = 0.f;

  for (int jt=0; jt<NJT; ++jt){
    const int jtg = jsplit*NJT + jt;               // global j-tile 0..127
    const size_t Pjt = ((size_t)(b*128 + jtg))*((size_t)4*NP*8);
    const size_t Vjt = ((size_t)(b*128 + jtg))*((size_t)4*CH*8);
    #pragma unroll
    for (int t=0;t<2;++t){
      bf16x8 Bh = ld8(&Pbuf[Pjt + ((size_t)((t*2+h)*NP) + i0w + l31)*8]);
      #pragma unroll
      for (int mt=0;mt<4;++mt){
        bf16x8 vh = ld8(&Vfrag[Vjt + (size_t)((t*2+h)*CH + mt*32 + l31)*8]);
        acc[mt] = mfma32(vh, Bh, acc[mt]);
      }
    }
  }
  u16* xp = xpart + ((size_t)(jsplit*NB + b))*(size_t)CH*NP;
  #pragma unroll
  for (int mt=0;mt<4;++mt){
    #pragma unroll
    for (int r=0;r<16;++r){
      int c = mt*32 + (r&3) + 8*(r>>2) + 4*h;
      xp[(size_t)c*NP + i0w + l31] = f2bf(acc[mt][r]);
    }
  }
}

// ---------------------------------------------------------------------------
// Kernel 5a': out = X + sum_{k<JSPLP} bf2f(xpart[k])
// ---------------------------------------------------------------------------
__global__ __launch_bounds__(256) void final8_kernel(
    const float* __restrict__ X, const u16* __restrict__ xpart,
    float* __restrict__ out)
{
  const size_t n = (size_t)NB*CH*NP;
  size_t idx = ((size_t)blockIdx.x*256 + threadIdx.x)*4;
  f32x4 s = *(const f32x4*)&X[idx];
  #pragma unroll
  for (int k=0;k<JSPLP;++k){
    us4 p = *(const us4*)&xpart[(size_t)k*n + idx];
    #pragma unroll
    for (int e=0;e<4;++e) s[e] += bf2f(p[e]);
  }
  *(f32x4*)&out[idx] = s;
}

// ---------------------------------------------------------------------------
// Kernel 5b (fallback, ws too small): flash attn (atomics into out).
// ---------------------------------------------------------------------------
__global__ __launch_bounds__(256,2) void attnf_kernel(
    const u16* __restrict__ Qhi, const u16* __restrict__ Qlo,
    const u16* __restrict__ Khi, const u16* __restrict__ Klo,
    const u16* __restrict__ Vthi,
    float* __restrict__ out)
{
  __shared__ u16 SK[2][2][32*CH];
  __shared__ u16 SV[2][4*CH*8];
  const int b = blockIdx.z, jsplit = blockIdx.y;
  const int tid = threadIdx.x, lane = tid&63, w = tid>>6;
  const int l31 = lane&31, h = lane>>5;
  const int i0w = blockIdx.x*128 + w*32;
  const bool hb1 = (h != 0);

  const int slot0 = tid, slot1 = tid + 256;
  const int kr0 = slot0&31, kc0 = slot0>>5, kr1 = slot1&31, kc1 = slot1>>5;
  const size_t kg0 = ((size_t)b*NP + kr0)*CH + kc0*8;
  const size_t kg1 = ((size_t)b*NP + kr1)*CH + kc1*8;
  const size_t vg0 = ((size_t)b*CH + (slot0&127))*NP + (slot0>>7)*8;
  const size_t vg1 = ((size_t)b*CH + (slot1&127))*NP + (slot1>>7)*8;
  const int lof0 = slot0*8, lof1 = slot1*8;

  const int jbase = jsplit*(NP/JSPLF);
  const int NJT = (NP/JSPLF)/32;

  auto stageK = [&](int t){
    size_t jofs = (size_t)(jbase + t*32)*CH;
    int bf = t&1;
    gll16(&Khi[kg0 + jofs], &SK[bf][0][lof0]);
    gll16(&Khi[kg1 + jofs], &SK[bf][0][lof1]);
    gll16(&Klo[kg0 + jofs], &SK[bf][1][lof0]);
    gll16(&Klo[kg1 + jofs], &SK[bf][1][lof1]);
  };
  auto stageV = [&](int t){
    int j0 = jbase + t*32;
    int bf = t&1;
    gll16(&Vthi[vg0 + j0], &SV[bf][lof0]);
    gll16(&Vthi[vg1 + j0], &SV[bf][lof1]);
  };

  bf16x8 qh[8], ql[8];
  #pragma unroll
  for (int ks=0;ks<8;++ks){
    size_t g = ((size_t)b*NP + i0w + l31)*CH + ks*16 + h*8;
    qh[ks] = ld8(&Qhi[g]); ql[ks] = ld8(&Qlo[g]);
  }

  auto computeS = [&](int t, f32x16& s){
    const u16* Kh = &SK[t&1][0][0];
    const u16* Kl = &SK[t&1][1][0];
    #pragma unroll
    for (int r=0;r<16;++r) s[r] = 0.f;
    #pragma unroll
    for (int ks=0;ks<8;++ks){
      int o = (ks*2+h)*256 + l31*8;
      bf16x8 ah = ld8(&Kh[o]);
      bf16x8 al = ld8(&Kl[o]);
      s = mfma32(ah, ql[ks], s);
      s = mfma32(al, qh[ks], s);
      s = mfma32(ah, qh[ks], s);
    }
  };

  f32x16 acc[4];
  #pragma unroll
  for (int mt=0;mt<4;++mt)
    #pragma unroll
    for (int r=0;r<16;++r) acc[mt][r] = 0.f;

  stageK(0); stageV(0); stageK(1);
  __syncthreads();
  f32x16 s;
  computeS(0, s);
  __syncthreads();

  for (int jt=0; jt<NJT; ++jt){
    const int cb = jt&1;
    if (jt+2 < NJT) stageK(jt+2);
    if (jt+1 < NJT) stageV(jt+1);

    float p[16];
    #pragma unroll
    for (int r=0;r<16;++r) p[r] = __expf(s[r]);

    if (jt+1 < NJT) computeS(jt+1, s);

    const u16* Vh = &SV[cb][0];
    #pragma unroll
    for (int t=0;t<2;++t){
      us8 fr = pfrag(&p[8*t], hb1);
      bf16x8 Bh; __builtin_memcpy(&Bh, &fr, 16);
      #pragma unroll
      for (int mt=0;mt<4;++mt){
        int o = (t*2+h)*1024 + (mt*32+l31)*8;
        bf16x8 vh = ld8(&Vh[o]);
        acc[mt] = mfma32(vh, Bh, acc[mt]);
      }
    }
    __syncthreads();
  }
  float* xp = out + (size_t)b*CH*NP;
  #pragma unroll
  for (int mt=0;mt<4;++mt){
    #pragma unroll
    for (int r=0;r<16;++r){
      int c = mt*32 + (r&3) + 8*(r>>2) + 4*h;
      atomicAdd(&xp[(size_t)c*NP + i0w + l31], acc[mt][r]);
    }
  }
}

extern "C" void kernel_launch(void* const* d_in, const int* in_sizes, int n_in,
                              void* d_out, int out_size, void* d_ws, size_t ws_size,
                              hipStream_t stream)
{
  const float* X  = (const float*)d_in[0];
  const float* Wq = (const float*)d_in[1];
  const float* bq = (const float*)d_in[2];
  const float* Wk = (const float*)d_in[3];
  const float* bk = (const float*)d_in[4];
  const float* Wv = (const float*)d_in[5];
  const float* bv = (const float*)d_in[6];
  float* outp = (float*)d_out;

  const size_t n = (size_t)NB*NP*CH;        // 2,097,152
  u16* Qhi = (u16*)d_ws;
  u16* Qlo = Qhi + n;
  u16* Khi = Qlo + n;
  u16* Klo = Khi + n;
  u16* Vthi = Klo + n;
  u16* Vtlo = Vthi + n;
  u16* Whi  = Vtlo + n;
  u16* Wlo  = Whi + 3*CH*CH;
  float* colpart = (float*)(Wlo + 3*CH*CH);      // ISPL*NB*NP floats
  u16* Pbuf = (u16*)(colpart + (size_t)ISPL*NB*NP);
  const size_t pelems = (size_t)NB*128*4*NP*8;   // 67,108,864 u16 = 128 MiB
  u16* Vfrag = Pbuf + pelems;                    // n u16 = 4 MiB
  u16* xpart = Vfrag + n;                        // JSPLP*n u16 = 32 MiB

  const size_t need = (size_t)((char*)xpart - (char*)d_ws)
                      + (size_t)JSPLP*n*sizeof(u16);
  const bool usep = (ws_size >= need);

  wsplit_kernel<<<dim3(CH*CH/256, 3),      256, 0, stream>>>(Wq, Wk, Wv, Whi, Wlo);
  proj_kernel  <<<dim3(NP/16, NB),         256, 0, stream>>>(X, Whi, Wlo, bq, bk, bv,
                                                             Qhi,Qlo, Khi,Klo, Vthi,Vtlo);
  if (usep){
    stats_kernel<true><<<dim3(NP/128, ISPL, NB), 256, 0, stream>>>(
        Qhi,Qlo, Khi,Klo, colpart, Pbuf);
    scalev_kernel<<<dim3(n/(256*8)),       256, 0, stream>>>(Vthi, Vtlo, colpart, Vfrag);
    attnp_kernel <<<dim3(NP/128, JSPLP, NB), 256, 0, stream>>>(Pbuf, Vfrag, xpart);
    final8_kernel<<<dim3(n/(256*4)),       256, 0, stream>>>(X, xpart, outp);
  } else {
    stats_kernel<false><<<dim3(NP/128, ISPL, NB), 256, 0, stream>>>(
        Qhi,Qlo, Khi,Klo, colpart, Pbuf);
    scalev_kernel<<<dim3(n/(256*8)),       256, 0, stream>>>(Vthi, Vtlo, colpart,
                                                             (u16*)nullptr);
    copyx_kernel <<<dim3(n/(256*4)),       256, 0, stream>>>(X, outp);
    attnf_kernel <<<dim3(NP/128, JSPLF, NB), 256, 0, stream>>>(
        Qhi,Qlo, Khi,Klo, Vthi, outp);
  }
}

// Round 20
// 217.846 us; speedup vs baseline: 1.1168x; 1.0192x over previous
//
#include <hip/hip_runtime.h>
#include <hip/hip_bf16.h>

// SelfAttention (B=4, C=128, H=W=64), fp32 I/O.
// out[b,c,i] = X[b,c,i] + sum_j exp(S[i,j]) * rinv_j * V[j,c],
//   S = Q K^T, rinv_j = 1/sum_i exp(S[i,j])   (softmax over query axis)
// S via split-bf16 (hi+lo) 3-term MFMA emulation (precision-critical).
// proj: 4 waves/block sharing one LDS X-tile.
// stats: LDS-shared Q staging (4-wave reuse), dbuf-pipelined, 32 j/wave,
// emits P=exp(S) in bf16 B-fragment image via shuffle-free 8B stores
// + column-sum partials. scalev: V' in A-fragment image. attnp:
// barrier-free LDS-free streaming P@V' GEMM, bf16 partials via plain
// stores (no atomics). final8 reduces.

typedef unsigned short u16;
typedef __attribute__((ext_vector_type(8))) __bf16 bf16x8;
typedef __attribute__((ext_vector_type(8))) unsigned short us8;
typedef __attribute__((ext_vector_type(4))) unsigned short us4;
typedef __attribute__((ext_vector_type(4))) float f32x4;
typedef __attribute__((ext_vector_type(16))) float f32x16;

#define NB 4
#define CH 128
#define NP 4096
#define ISPL 16   // stats i-splits
#define JSPLF 4   // fallback attn j-splits
#define JSPLP 8   // P-path attn j-splits

__device__ __forceinline__ float bf2f(u16 b){ union{float f;unsigned u;}v; v.u=((unsigned)b)<<16; return v.f; }
__device__ __forceinline__ u16 f2bf(float f){ union{float f;unsigned u;}v; v.f=f; unsigned r=v.u + 0x7FFFu + ((v.u>>16)&1u); return (u16)(r>>16); }

__device__ __forceinline__ f32x4 mfma16(bf16x8 a, bf16x8 b, f32x4 c){
  return __builtin_amdgcn_mfma_f32_16x16x32_bf16(a, b, c, 0, 0, 0);
}
__device__ __forceinline__ f32x16 mfma32(bf16x8 a, bf16x8 b, f32x16 c){
  return __builtin_amdgcn_mfma_f32_32x32x16_bf16(a, b, c, 0, 0, 0);
}
__device__ __forceinline__ bf16x8 ld8(const u16* p){
  union { us8 u; bf16x8 b; } v; v.u = *(const us8*)p; return v.b;
}
__device__ __forceinline__ void split8(const float* p, bf16x8& h, bf16x8& l){
  union { us8 u; bf16x8 b; } uh, ul;
  #pragma unroll
  for (int e=0;e<8;++e){
    float f = p[e];
    u16 hb = f2bf(f);
    uh.u[e] = hb;
    ul.u[e] = f2bf(f - bf2f(hb));
  }
  h = uh.b; l = ul.b;
}
__device__ __forceinline__ unsigned pk2(float a, float b){
  float2 f2; f2.x = a; f2.y = b;
  __hip_bfloat162 hb = __float22bfloat162_rn(f2);
  unsigned u; __builtin_memcpy(&u, &hb, 4);
  return u;
}
// C/D-layout p[8] (one k-tile) -> P^T B-fragment (lane n=i, k=h*8+e).
// (used by the fallback flash kernel only)
__device__ __forceinline__ us8 pfrag(const float* p, bool hb1){
  unsigned hA = pk2(p[0], p[1]);
  unsigned hB = pk2(p[2], p[3]);
  unsigned hC = pk2(p[4], p[5]);
  unsigned hD = pk2(p[6], p[7]);
  unsigned s0h = hb1? hA:hC, s1h = hb1? hB:hD;
  unsigned r0h = __shfl_xor(s0h, 32), r1h = __shfl_xor(s1h, 32);
  unsigned dh[4];
  dh[0] = hb1? r0h : hA;  dh[1] = hb1? r1h : hB;
  dh[2] = hb1? hC  : r0h; dh[3] = hb1? hD  : r1h;
  us8 o; __builtin_memcpy(&o, dh, 16); return o;
}
__device__ __forceinline__ void gll16(const void* g, void* l){
  __builtin_amdgcn_global_load_lds((const __attribute__((address_space(1))) void*)g,
                                   (__attribute__((address_space(3))) void*)l, 16, 0, 0);
}

// ---------------------------------------------------------------------------
// Kernel 0: pre-split the three 128x128 weight matrices into bf16 hi/lo.
// ---------------------------------------------------------------------------
__global__ __launch_bounds__(256) void wsplit_kernel(
    const float* __restrict__ Wq, const float* __restrict__ Wk,
    const float* __restrict__ Wv, u16* __restrict__ Whi, u16* __restrict__ Wlo)
{
  const int m = blockIdx.y;
  const float* W = (m==0) ? Wq : (m==1) ? Wk : Wv;
  int i = blockIdx.x*256 + threadIdx.x;
  float f = W[i];
  u16 hb = f2bf(f);
  Whi[m*CH*CH + i] = hb;
  Wlo[m*CH*CH + i] = f2bf(f - bf2f(hb));
}

// ---------------------------------------------------------------------------
// Kernel 1: projections. 256-thread blocks: 4 waves share one 16-pixel
// X-tile in LDS; wave w computes nt {2w,2w+1} of Q and K, mt {2w,2w+1} of V.
// ---------------------------------------------------------------------------
__global__ __launch_bounds__(256) void proj_kernel(
    const float* __restrict__ X,
    const u16* __restrict__ Whi, const u16* __restrict__ Wlo,
    const float* __restrict__ bq, const float* __restrict__ bk,
    const float* __restrict__ bv,
    u16* __restrict__ Qhi, u16* __restrict__ Qlo,
    u16* __restrict__ Khi, u16* __restrict__ Klo,
    u16* __restrict__ Vthi, u16* __restrict__ Vtlo)
{
  __shared__ float XT[16][CH+4];
  const int b = blockIdx.y, p0 = blockIdx.x*16;
  const int tid = threadIdx.x, lane = tid&63, w = tid>>6;
  {
    int c = tid & 127, half = tid >> 7;
    const float* src = X + ((size_t)b*CH + c)*NP + p0 + half*8;
    f32x4 v0 = *(const f32x4*)src;
    f32x4 v1 = *(const f32x4*)(src + 4);
    #pragma unroll
    for (int p=0;p<4;++p) XT[half*8 + p][c] = v0[p];
    #pragma unroll
    for (int p=0;p<4;++p) XT[half*8 + 4 + p][c] = v1[p];
  }
  __syncthreads();
  const int l15 = lane&15, quad = lane>>4;
  bf16x8 xh[4], xl[4];
  #pragma unroll
  for (int s=0;s<4;++s) split8(&XT[l15][s*32+quad*8], xh[s], xl[s]);

  const float* bm[2] = {bq, bk};
  u16* OH[2] = {Qhi, Khi};
  u16* OL[2] = {Qlo, Klo};
  #pragma unroll
  for (int m=0;m<2;++m){
    const u16* WH = Whi + m*CH*CH;
    const u16* WL = Wlo + m*CH*CH;
    #pragma unroll
    for (int nn=0;nn<2;++nn){
      int nt = w*2 + nn;
      f32x4 a = {0.f,0.f,0.f,0.f};
      #pragma unroll
      for (int s=0;s<4;++s){
        size_t g = (size_t)(nt*16+l15)*CH + s*32 + quad*8;
        bf16x8 wh = ld8(&WH[g]), wl = ld8(&WL[g]);
        a = mfma16(xh[s], wl, a);
        a = mfma16(xl[s], wh, a);
        a = mfma16(xh[s], wh, a);
      }
      int o = nt*16 + l15;
      float bias = bm[m][o];
      #pragma unroll
      for (int r=0;r<4;++r){
        int i = p0 + quad*4 + r;
        float q = a[r] + bias;
        u16 hb = f2bf(q);
        size_t idx = ((size_t)b*NP + i)*CH + o;
        OH[m][idx] = hb;
        OL[m][idx] = f2bf(q - bf2f(hb));
      }
    }
  }
  const u16* WH = Whi + 2*CH*CH;
  const u16* WL = Wlo + 2*CH*CH;
  #pragma unroll
  for (int mm=0;mm<2;++mm){
    int mt = w*2 + mm;
    f32x4 a = {0.f,0.f,0.f,0.f};
    #pragma unroll
    for (int s=0;s<4;++s){
      size_t g = (size_t)(mt*16+l15)*CH + s*32 + quad*8;
      bf16x8 wh = ld8(&WH[g]), wl = ld8(&WL[g]);
      a = mfma16(wh, xl[s], a);
      a = mfma16(wl, xh[s], a);
      a = mfma16(wh, xh[s], a);
    }
    #pragma unroll
    for (int r=0;r<4;++r){
      int co = mt*16 + quad*4 + r;
      float v = a[r] + bv[co];
      u16 hb = f2bf(v);
      size_t idx = ((size_t)b*CH + co)*NP + p0 + l15;
      Vthi[idx] = hb;
      Vtlo[idx] = f2bf(v - bf2f(hb));
    }
  }
}

// ---------------------------------------------------------------------------
// Kernel 2: S^T = K Q^T (32x32x16, 3-term), LDS-shared Q staging (dbuf,
// software-pipelined), 32 j per wave. Column sums always; if STOREP, also
// emit P=exp(S) as bf16 B-fragment image via SHUFFLE-FREE 8B stores:
// lane's C/D values map to 4 contiguous 4-elem groups at
// Pbuf[Pjt + (g*NP + i)*8 + 4h]  (h0 lanes own e0-3, h1 own e4-7).
// ---------------------------------------------------------------------------
template<bool STOREP>
__global__ __launch_bounds__(256,3) void stats_kernel(
    const u16* __restrict__ Qhi, const u16* __restrict__ Qlo,
    const u16* __restrict__ Khi, const u16* __restrict__ Klo,
    float* __restrict__ colpart, u16* __restrict__ Pbuf)
{
  __shared__ u16 SQ[2][2][32*CH];
  const int b = blockIdx.z, isplit = blockIdx.y;
  const int tid = threadIdx.x, lane = tid&63, w = tid>>6;
  const int l31 = lane&31, h = lane>>5;
  const int j0w = blockIdx.x*128 + w*32;

  const int slot0 = w*128 + lane, slot1 = slot0 + 64;
  const int qr0 = slot0&31, qc0 = slot0>>5, qr1 = slot1&31, qc1 = slot1>>5;
  const size_t qg0 = ((size_t)b*NP + qr0)*CH + qc0*8;
  const size_t qg1 = ((size_t)b*NP + qr1)*CH + qc1*8;
  const int lof0 = slot0*8, lof1 = slot1*8;

  bf16x8 kh[8], kl[8];
  #pragma unroll
  for (int ks=0;ks<8;++ks){
    size_t g = ((size_t)b*NP + j0w + l31)*CH + ks*16 + h*8;
    kh[ks] = ld8(&Khi[g]);
    kl[ks] = ld8(&Klo[g]);
  }

  const int ibase = isplit*(NP/ISPL);
  const int NCH = (NP/ISPL)/32;     // 8 chunks
  const size_t Pjt = ((size_t)(b*128 + blockIdx.x*4 + w))*((size_t)4*NP*8);

  auto stageQ = [&](int t){
    size_t iofs = (size_t)(ibase + t*32)*CH;
    int bf = t&1;
    gll16(&Qhi[qg0 + iofs], &SQ[bf][0][lof0]);
    gll16(&Qhi[qg1 + iofs], &SQ[bf][0][lof1]);
    gll16(&Qlo[qg0 + iofs], &SQ[bf][1][lof0]);
    gll16(&Qlo[qg1 + iofs], &SQ[bf][1][lof1]);
  };
  auto computeS = [&](int t, f32x16& s){
    const u16* Qh = &SQ[t&1][0][0];
    const u16* Ql = &SQ[t&1][1][0];
    #pragma unroll
    for (int r=0;r<16;++r) s[r] = 0.f;
    #pragma unroll
    for (int ks=0;ks<8;++ks){
      int o = (ks*2+h)*256 + l31*8;
      bf16x8 qbh = ld8(&Qh[o]);
      bf16x8 qbl = ld8(&Ql[o]);
      s = mfma32(kh[ks], qbl, s);
      s = mfma32(kl[ks], qbh, s);
      s = mfma32(kh[ks], qbh, s);
    }
  };

  stageQ(0); if (NCH > 1) stageQ(1);
  __syncthreads();
  f32x16 s;
  computeS(0, s);
  __syncthreads();

  float scol[16];
  #pragma unroll
  for (int r=0;r<16;++r) scol[r] = 0.f;

  for (int ic=0; ic<NCH; ++ic){
    if (ic+2 < NCH) stageQ(ic+2);
    float p[16];
    #pragma unroll
    for (int r=0;r<16;++r){ p[r] = __expf(s[r]); scol[r] += p[r]; }
    if (STOREP){
      int iglob = ibase + ic*32 + l31;
      #pragma unroll
      for (int g=0; g<4; ++g){
        unsigned dd[2];
        dd[0] = pk2(p[4*g],   p[4*g+1]);
        dd[1] = pk2(p[4*g+2], p[4*g+3]);
        us4 v; __builtin_memcpy(&v, dd, 8);
        *(us4*)&Pbuf[Pjt + ((size_t)(g*NP) + iglob)*8 + 4*h] = v;
      }
    }
    if (ic+1 < NCH) computeS(ic+1, s);
    __syncthreads();
  }
  #pragma unroll
  for (int m=1; m<32; m<<=1){
    #pragma unroll
    for (int r=0;r<16;++r) scol[r] += __shfl_xor(scol[r], m);
  }
  if (l31 == 0){
    #pragma unroll
    for (int r=0;r<16;++r){
      int j = j0w + (r&3) + 8*(r>>2) + 4*h;
      colpart[((size_t)(isplit*NB + b))*NP + j] = scol[r];
    }
  }
}

// ---------------------------------------------------------------------------
// Kernel 3: V' = rinv_j * V -> bf16: in-place hi (for fallback) AND, when
// Vfrag != nullptr, the A-fragment image Vfrag[b][jtile][kchunk(4)][c(128)]x8.
// ---------------------------------------------------------------------------
__global__ __launch_bounds__(256) void scalev_kernel(
    u16* __restrict__ Vthi, const u16* __restrict__ Vtlo,
    const float* __restrict__ colpart, u16* __restrict__ Vfrag)
{
  size_t t = (size_t)blockIdx.x*256 + threadIdx.x;
  size_t base = t*8;
  int bc = (int)(base >> 12);
  int b  = bc >> 7;
  int c  = bc & 127;
  int j0 = (int)(base & (NP-1));
  f32x4 s0 = {0.f,0.f,0.f,0.f}, s1 = {0.f,0.f,0.f,0.f};
  #pragma unroll
  for (int k=0;k<ISPL;++k){
    const float* cp = &colpart[((size_t)(k*NB + b))*NP + j0];
    f32x4 a0 = *(const f32x4*)cp;
    f32x4 a1 = *(const f32x4*)(cp+4);
    #pragma unroll
    for (int e=0;e<4;++e){ s0[e]+=a0[e]; s1[e]+=a1[e]; }
  }
  us8 hh = *(const us8*)&Vthi[base];
  us8 ll = *(const us8*)&Vtlo[base];
  us8 oh;
  #pragma unroll
  for (int e=0;e<8;++e){
    float r = 1.0f / (e<4 ? s0[e] : s1[e-4]);
    float v = (bf2f(hh[e]) + bf2f(ll[e])) * r;
    oh[e] = f2bf(v);
  }
  *(us8*)&Vthi[base] = oh;
  if (Vfrag){
    int jt = j0 >> 5;
    int kc = ((j0 >> 4) & 1)*2 + ((j0 >> 3) & 1);
    size_t o = (((size_t)(b*128 + jt))*4 + kc)*((size_t)CH*8) + (size_t)c*8;
    *(us8*)&Vfrag[o] = oh;
  }
}

// ---------------------------------------------------------------------------
// Kernel 4: out := X   (fallback path seed only)
// ---------------------------------------------------------------------------
__global__ __launch_bounds__(256) void copyx_kernel(
    const float* __restrict__ X, float* __restrict__ out)
{
  size_t idx = ((size_t)blockIdx.x*256 + threadIdx.x)*4;
  *(f32x4*)&out[idx] = *(const f32x4*)&X[idx];
}

// ---------------------------------------------------------------------------
// Kernel 5a (P path): barrier-free, LDS-free streaming P@V'.
// Both operands are fragment-image arrays (all loads coalesced 16B/lane).
// Partials stored as bf16 (plain stores, no atomics).
// ---------------------------------------------------------------------------
__global__ __launch_bounds__(256,4) void attnp_kernel(
    const u16* __restrict__ Pbuf, const u16* __restrict__ Vfrag,
    u16* __restrict__ xpart)
{
  const int b = blockIdx.z, jsplit = blockIdx.y;
  const int tid = threadIdx.x, lane = tid&63, w = tid>>6;
  const int l31 = lane&31, h = lane>>5;
  const int i0w = blockIdx.x*128 + w*32;

  const int NJT = (NP/JSPLP)/32;   // 16 j-tiles of 32

  f32x16 acc[4];
  #pragma unroll
  for (int mt=0;mt<4;++mt)
    #pragma unroll
    for (int r=0;r<16;++r) acc[mt][r] = 0.f;

  for (int jt=0; jt<NJT; ++jt){
    const int jtg = jsplit*NJT + jt;               // global j-tile 0..127
    const size_t Pjt = ((size_t)(b*128 + jtg))*((size_t)4*NP*8);
    const size_t Vjt = ((size_t)(b*128 + jtg))*((size_t)4*CH*8);
    #pragma unroll
    for (int t=0;t<2;++t){
      bf16x8 Bh = ld8(&Pbuf[Pjt + ((size_t)((t*2+h)*NP) + i0w + l31)*8]);
      #pragma unroll
      for (int mt=0;mt<4;++mt){
        bf16x8 vh = ld8(&Vfrag[Vjt + (size_t)((t*2+h)*CH + mt*32 + l31)*8]);
        acc[mt] = mfma32(vh, Bh, acc[mt]);
      }
    }
  }
  u16* xp = xpart + ((size_t)(jsplit*NB + b))*(size_t)CH*NP;
  #pragma unroll
  for (int mt=0;mt<4;++mt){
    #pragma unroll
    for (int r=0;r<16;++r){
      int c = mt*32 + (r&3) + 8*(r>>2) + 4*h;
      xp[(size_t)c*NP + i0w + l31] = f2bf(acc[mt][r]);
    }
  }
}

// ---------------------------------------------------------------------------
// Kernel 5a': out = X + sum_{k<JSPLP} bf2f(xpart[k])
// ---------------------------------------------------------------------------
__global__ __launch_bounds__(256) void final8_kernel(
    const float* __restrict__ X, const u16* __restrict__ xpart,
    float* __restrict__ out)
{
  const size_t n = (size_t)NB*CH*NP;
  size_t idx = ((size_t)blockIdx.x*256 + threadIdx.x)*4;
  f32x4 s = *(const f32x4*)&X[idx];
  #pragma unroll
  for (int k=0;k<JSPLP;++k){
    us4 p = *(const us4*)&xpart[(size_t)k*n + idx];
    #pragma unroll
    for (int e=0;e<4;++e) s[e] += bf2f(p[e]);
  }
  *(f32x4*)&out[idx] = s;
}

// ---------------------------------------------------------------------------
// Kernel 5b (fallback, ws too small): flash attn (atomics into out).
// ---------------------------------------------------------------------------
__global__ __launch_bounds__(256,2) void attnf_kernel(
    const u16* __restrict__ Qhi, const u16* __restrict__ Qlo,
    const u16* __restrict__ Khi, const u16* __restrict__ Klo,
    const u16* __restrict__ Vthi,
    float* __restrict__ out)
{
  __shared__ u16 SK[2][2][32*CH];
  __shared__ u16 SV[2][4*CH*8];
  const int b = blockIdx.z, jsplit = blockIdx.y;
  const int tid = threadIdx.x, lane = tid&63, w = tid>>6;
  const int l31 = lane&31, h = lane>>5;
  const int i0w = blockIdx.x*128 + w*32;
  const bool hb1 = (h != 0);

  const int slot0 = tid, slot1 = tid + 256;
  const int kr0 = slot0&31, kc0 = slot0>>5, kr1 = slot1&31, kc1 = slot1>>5;
  const size_t kg0 = ((size_t)b*NP + kr0)*CH + kc0*8;
  const size_t kg1 = ((size_t)b*NP + kr1)*CH + kc1*8;
  const size_t vg0 = ((size_t)b*CH + (slot0&127))*NP + (slot0>>7)*8;
  const size_t vg1 = ((size_t)b*CH + (slot1&127))*NP + (slot1>>7)*8;
  const int lof0 = slot0*8, lof1 = slot1*8;

  const int jbase = jsplit*(NP/JSPLF);
  const int NJT = (NP/JSPLF)/32;

  auto stageK = [&](int t){
    size_t jofs = (size_t)(jbase + t*32)*CH;
    int bf = t&1;
    gll16(&Khi[kg0 + jofs], &SK[bf][0][lof0]);
    gll16(&Khi[kg1 + jofs], &SK[bf][0][lof1]);
    gll16(&Klo[kg0 + jofs], &SK[bf][1][lof0]);
    gll16(&Klo[kg1 + jofs], &SK[bf][1][lof1]);
  };
  auto stageV = [&](int t){
    int j0 = jbase + t*32;
    int bf = t&1;
    gll16(&Vthi[vg0 + j0], &SV[bf][lof0]);
    gll16(&Vthi[vg1 + j0], &SV[bf][lof1]);
  };

  bf16x8 qh[8], ql[8];
  #pragma unroll
  for (int ks=0;ks<8;++ks){
    size_t g = ((size_t)b*NP + i0w + l31)*CH + ks*16 + h*8;
    qh[ks] = ld8(&Qhi[g]); ql[ks] = ld8(&Qlo[g]);
  }

  auto computeS = [&](int t, f32x16& s){
    const u16* Kh = &SK[t&1][0][0];
    const u16* Kl = &SK[t&1][1][0];
    #pragma unroll
    for (int r=0;r<16;++r) s[r] = 0.f;
    #pragma unroll
    for (int ks=0;ks<8;++ks){
      int o = (ks*2+h)*256 + l31*8;
      bf16x8 ah = ld8(&Kh[o]);
      bf16x8 al = ld8(&Kl[o]);
      s = mfma32(ah, ql[ks], s);
      s = mfma32(al, qh[ks], s);
      s = mfma32(ah, qh[ks], s);
    }
  };

  f32x16 acc[4];
  #pragma unroll
  for (int mt=0;mt<4;++mt)
    #pragma unroll
    for (int r=0;r<16;++r) acc[mt][r] = 0.f;

  stageK(0); stageV(0); stageK(1);
  __syncthreads();
  f32x16 s;
  computeS(0, s);
  __syncthreads();

  for (int jt=0; jt<NJT; ++jt){
    const int cb = jt&1;
    if (jt+2 < NJT) stageK(jt+2);
    if (jt+1 < NJT) stageV(jt+1);

    float p[16];
    #pragma unroll
    for (int r=0;r<16;++r) p[r] = __expf(s[r]);

    if (jt+1 < NJT) computeS(jt+1, s);

    const u16* Vh = &SV[cb][0];
    #pragma unroll
    for (int t=0;t<2;++t){
      us8 fr = pfrag(&p[8*t], hb1);
      bf16x8 Bh; __builtin_memcpy(&Bh, &fr, 16);
      #pragma unroll
      for (int mt=0;mt<4;++mt){
        int o = (t*2+h)*1024 + (mt*32+l31)*8;
        bf16x8 vh = ld8(&Vh[o]);
        acc[mt] = mfma32(vh, Bh, acc[mt]);
      }
    }
    __syncthreads();
  }
  float* xp = out + (size_t)b*CH*NP;
  #pragma unroll
  for (int mt=0;mt<4;++mt){
    #pragma unroll
    for (int r=0;r<16;++r){
      int c = mt*32 + (r&3) + 8*(r>>2) + 4*h;
      atomicAdd(&xp[(size_t)c*NP + i0w + l31], acc[mt][r]);
    }
  }
}

extern "C" void kernel_launch(void* const* d_in, const int* in_sizes, int n_in,
                              void* d_out, int out_size, void* d_ws, size_t ws_size,
                              hipStream_t stream)
{
  const float* X  = (const float*)d_in[0];
  const float* Wq = (const float*)d_in[1];
  const float* bq = (const float*)d_in[2];
  const float* Wk = (const float*)d_in[3];
  const float* bk = (const float*)d_in[4];
  const float* Wv = (const float*)d_in[5];
  const float* bv = (const float*)d_in[6];
  float* outp = (float*)d_out;

  const size_t n = (size_t)NB*NP*CH;        // 2,097,152
  u16* Qhi = (u16*)d_ws;
  u16* Qlo = Qhi + n;
  u16* Khi = Qlo + n;
  u16* Klo = Khi + n;
  u16* Vthi = Klo + n;
  u16* Vtlo = Vthi + n;
  u16* Whi  = Vtlo + n;
  u16* Wlo  = Whi + 3*CH*CH;
  float* colpart = (float*)(Wlo + 3*CH*CH);      // ISPL*NB*NP floats
  u16* Pbuf = (u16*)(colpart + (size_t)ISPL*NB*NP);
  const size_t pelems = (size_t)NB*128*4*NP*8;   // 67,108,864 u16 = 128 MiB
  u16* Vfrag = Pbuf + pelems;                    // n u16 = 4 MiB
  u16* xpart = Vfrag + n;                        // JSPLP*n u16 = 32 MiB

  const size_t need = (size_t)((char*)xpart - (char*)d_ws)
                      + (size_t)JSPLP*n*sizeof(u16);
  const bool usep = (ws_size >= need);

  wsplit_kernel<<<dim3(CH*CH/256, 3),      256, 0, stream>>>(Wq, Wk, Wv, Whi, Wlo);
  proj_kernel  <<<dim3(NP/16, NB),         256, 0, stream>>>(X, Whi, Wlo, bq, bk, bv,
                                                             Qhi,Qlo, Khi,Klo, Vthi,Vtlo);
  if (usep){
    stats_kernel<true><<<dim3(NP/128, ISPL, NB), 256, 0, stream>>>(
        Qhi,Qlo, Khi,Klo, colpart, Pbuf);
    scalev_kernel<<<dim3(n/(256*8)),       256, 0, stream>>>(Vthi, Vtlo, colpart, Vfrag);
    attnp_kernel <<<dim3(NP/128, JSPLP, NB), 256, 0, stream>>>(Pbuf, Vfrag, xpart);
    final8_kernel<<<dim3(n/(256*4)),       256, 0, stream>>>(X, xpart, outp);
  } else {
    stats_kernel<false><<<dim3(NP/128, ISPL, NB), 256, 0, stream>>>(
        Qhi,Qlo, Khi,Klo, colpart, Pbuf);
    scalev_kernel<<<dim3(n/(256*8)),       256, 0, stream>>>(Vthi, Vtlo, colpart,
                                                             (u16*)nullptr);
    copyx_kernel <<<dim3(n/(256*4)),       256, 0, stream>>>(X, outp);
    attnf_kernel <<<dim3(NP/128, JSPLF, NB), 256, 0, stream>>>(
        Qhi,Qlo, Khi,Klo, Vthi, outp);
  }
}